// Round 1
// baseline (1264.440 us; speedup 1.0000x reference)
//
#include <hip/hip_runtime.h>
#include <cstdint>
#include <cstddef>

#define NU 100000
#define NI 50000
#define NTOT 150000
#define EDIM 64
#define NE 1000000
#define NLAYERS 3
#define SCAN_CHUNK 1024
#define NBLK ((NTOT + SCAN_CHUNK - 1) / SCAN_CHUNK)   // 147

// ---------------- utility kernels ----------------

__global__ void k_zero_int(int* __restrict__ p, int n) {
    int i = blockIdx.x * blockDim.x + threadIdx.x;
    if (i < n) p[i] = 0;
}

__global__ void k_count(const int* __restrict__ eu, const int* __restrict__ ei,
                        int* __restrict__ deg) {
    int e = blockIdx.x * blockDim.x + threadIdx.x;
    if (e < NE) {
        atomicAdd(&deg[eu[e]], 1);
        atomicAdd(&deg[NU + ei[e]], 1);
    }
}

// block sums for scan: each block covers 1024 elements, 256 threads x 4
__global__ void k_blocksum(const int* __restrict__ deg, int* __restrict__ partials) {
    __shared__ int sm[256];
    int b = blockIdx.x, t = threadIdx.x;
    int base = b * SCAN_CHUNK + t * 4;
    int s = 0;
#pragma unroll
    for (int j = 0; j < 4; ++j) {
        int idx = base + j;
        if (idx < NTOT) s += deg[idx];
    }
    sm[t] = s;
    __syncthreads();
    for (int off = 128; off > 0; off >>= 1) {
        if (t < off) sm[t] += sm[t + off];
        __syncthreads();
    }
    if (t == 0) partials[b] = sm[0];
}

// exclusive scan of the (<=256) partials, single block
__global__ void k_scanpartials(int* __restrict__ partials, int nblk) {
    __shared__ int sm[256];
    int t = threadIdx.x;
    int v = (t < nblk) ? partials[t] : 0;
    sm[t] = v;
    __syncthreads();
    for (int off = 1; off < 256; off <<= 1) {
        int tmp = (t >= off) ? sm[t - off] : 0;
        __syncthreads();
        sm[t] += tmp;
        __syncthreads();
    }
    if (t < nblk) partials[t] = sm[t] - v;   // exclusive
}

// final scan: write exclusive start positions (and cursor copy)
__global__ void k_scanfinal(const int* __restrict__ deg, const int* __restrict__ partials,
                            int* __restrict__ start, int* __restrict__ cursor) {
    __shared__ int sm[256];
    int b = blockIdx.x, t = threadIdx.x;
    int base = b * SCAN_CHUNK + t * 4;
    int v[4];
    int s = 0;
#pragma unroll
    for (int j = 0; j < 4; ++j) {
        int idx = base + j;
        v[j] = (idx < NTOT) ? deg[idx] : 0;
        s += v[j];
    }
    sm[t] = s;
    __syncthreads();
    for (int off = 1; off < 256; off <<= 1) {
        int tmp = (t >= off) ? sm[t - off] : 0;
        __syncthreads();
        sm[t] += tmp;
        __syncthreads();
    }
    int excl = partials[b] + sm[t] - s;
#pragma unroll
    for (int j = 0; j < 4; ++j) {
        int idx = base + j;
        if (idx < NTOT) {
            start[idx] = excl;
            cursor[idx] = excl;
            excl += v[j];
        }
    }
}

__global__ void k_scales(const int* __restrict__ deg, float* __restrict__ isq,
                         float* __restrict__ inv) {
    int i = blockIdx.x * blockDim.x + threadIdx.x;
    if (i < NTOT) {
        float d = (float)deg[i];
        isq[i] = d > 0.f ? 1.0f / sqrtf(d) : 0.f;
        inv[i] = d > 0.f ? 1.0f / d : 0.f;
    }
}

__global__ void k_fill(const int* __restrict__ eu, const int* __restrict__ ei,
                       int* __restrict__ cursor, int* __restrict__ csr) {
    int e = blockIdx.x * blockDim.x + threadIdx.x;
    if (e < NE) {
        int u = eu[e];
        int v = NU + ei[e];
        int p1 = atomicAdd(&cursor[u], 1);
        csr[p1] = v;
        int p2 = atomicAdd(&cursor[v], 1);
        csr[p2] = u;
    }
}

// init all_embs = concat(u_emb, i_emb); out accumulator likewise (layer-0 term)
__global__ void k_init(const float* __restrict__ ue, const float* __restrict__ ie,
                       float* __restrict__ embs, float* __restrict__ outacc) {
    int i = blockIdx.x * blockDim.x + threadIdx.x;
    const int n4 = NTOT * EDIM / 4;
    if (i < n4) {
        const int nu4 = NU * EDIM / 4;
        float4 v = (i < nu4) ? ((const float4*)ue)[i] : ((const float4*)ie)[i - nu4];
        ((float4*)embs)[i] = v;
        ((float4*)outacc)[i] = v;
    }
}

// ---------------- sparse gather (pull) ----------------
// SS=true : out[n] = sA[n] * sum_{m in nbr(n)} sB[m] * in[m]   (E pass)
// SS=false: out[n] = sA[n] * sum_{m in nbr(n)} in[m]           (Y pass)
template <bool SS>
__global__ __launch_bounds__(256) void k_gather(
    const float* __restrict__ in, float* __restrict__ out,
    const int* __restrict__ csr, const int* __restrict__ start,
    const int* __restrict__ deg, const float* __restrict__ sA,
    const float* __restrict__ sB) {
    int gw = (blockIdx.x * 256 + threadIdx.x) >> 6;   // global wave = row
    int lane = threadIdx.x & 63;                      // lane = embedding dim
    if (gw >= NTOT) return;
    int s0 = start[gw];
    int dg = deg[gw];
    float acc = 0.f;
    for (int j0 = 0; j0 < dg; j0 += 64) {
        int lim = min(64, dg - j0);
        int nidx = 0;
        float sb = 0.f;
        if (lane < lim) {
            nidx = csr[s0 + j0 + lane];
            if (SS) sb = sB[nidx];
        }
        int j = 0;
        for (; j + 4 <= lim; j += 4) {
            int m0 = __shfl(nidx, j);
            int m1 = __shfl(nidx, j + 1);
            int m2 = __shfl(nidx, j + 2);
            int m3 = __shfl(nidx, j + 3);
            float v0 = in[m0 * EDIM + lane];
            float v1 = in[m1 * EDIM + lane];
            float v2 = in[m2 * EDIM + lane];
            float v3 = in[m3 * EDIM + lane];
            if (SS) {
                float w0 = __shfl(sb, j), w1 = __shfl(sb, j + 1);
                float w2 = __shfl(sb, j + 2), w3 = __shfl(sb, j + 3);
                acc += w0 * v0;
                acc += w1 * v1;
                acc += w2 * v2;
                acc += w3 * v3;
            } else {
                acc += v0;
                acc += v1;
                acc += v2;
                acc += v3;
            }
        }
        for (; j < lim; ++j) {
            int m = __shfl(nidx, j);
            float v = in[m * EDIM + lane];
            if (SS) {
                float w = __shfl(sb, j);
                acc += w * v;
            } else {
                acc += v;
            }
        }
    }
    out[gw * EDIM + lane] = sA[gw] * acc;
}

// ---------------- dense per-row update ----------------
// one wave per block; lane d keeps W row d (both matrices) in registers.
__global__ __launch_bounds__(64) void k_dense(
    float* __restrict__ embs, const float* __restrict__ g,
    float* __restrict__ outacc, const float* __restrict__ Wg,
    const float* __restrict__ bg, const float* __restrict__ Wb,
    const float* __restrict__ bb, float finalScale) {
    int lane = threadIdx.x;
    float wg[64], wb[64];
#pragma unroll
    for (int k = 0; k < 64; k += 4) {
        float4 a4 = *(const float4*)&Wg[lane * 64 + k];
        wg[k] = a4.x; wg[k + 1] = a4.y; wg[k + 2] = a4.z; wg[k + 3] = a4.w;
        float4 b4 = *(const float4*)&Wb[lane * 64 + k];
        wb[k] = b4.x; wb[k + 1] = b4.y; wb[k + 2] = b4.z; wb[k + 3] = b4.w;
    }
    float bgd = bg[lane], bbd = bb[lane];
    __shared__ float gs[64];
    __shared__ float as[64];
    for (int r = blockIdx.x; r < NTOT; r += gridDim.x) {
        float a = embs[r * 64 + lane];
        float gv = g[r * 64 + lane];
        gs[lane] = gv;
        as[lane] = a * gv;
        __syncthreads();
        float s1 = 0.f, s2 = 0.f;
#pragma unroll
        for (int k = 0; k < 64; k += 4) {
            float4 g4 = *(const float4*)&gs[k];
            float4 a4 = *(const float4*)&as[k];
            s1 += g4.x * wg[k] + g4.y * wg[k + 1] + g4.z * wg[k + 2] + g4.w * wg[k + 3];
            s2 += a4.x * wb[k] + a4.y * wb[k + 1] + a4.z * wb[k + 2] + a4.w * wb[k + 3];
        }
        float e1 = s1 + bgd + a;
        e1 = e1 >= 0.f ? e1 : 0.2f * e1;
        float e2 = s2 + bbd;
        e2 = e2 >= 0.f ? e2 : 0.2f * e2;
        float nv = e1 + e2;
        float ss = nv * nv;
#pragma unroll
        for (int off = 32; off > 0; off >>= 1) ss += __shfl_xor(ss, off, 64);
        float norm = sqrtf(ss);
        float rr = nv / fmaxf(norm, 1e-12f);
        embs[r * 64 + lane] = rr;
        outacc[r * 64 + lane] = (outacc[r * 64 + lane] + rr) * finalScale;
        __syncthreads();
    }
}

// ---------------- launch ----------------

extern "C" void kernel_launch(void* const* d_in, const int* in_sizes, int n_in,
                              void* d_out, int out_size, void* d_ws, size_t ws_size,
                              hipStream_t stream) {
    const float* u_emb = (const float*)d_in[0];
    const float* i_emb = (const float*)d_in[1];
    const float* Wgc = (const float*)d_in[2];
    const float* bgc = (const float*)d_in[3];
    const float* Wbi = (const float*)d_in[4];
    const float* bbi = (const float*)d_in[5];
    const int* edge_u = (const int*)d_in[6];
    const int* edge_i = (const int*)d_in[7];
    float* out = (float*)d_out;

    char* w = (char*)d_ws;
    auto alloc = [&](size_t bytes) {
        char* p = w;
        w += (bytes + 255) & ~(size_t)255;
        return p;
    };
    int* deg = (int*)alloc((size_t)NTOT * 4);
    int* start = (int*)alloc((size_t)NTOT * 4);
    int* cursor = (int*)alloc((size_t)NTOT * 4);
    int* partials = (int*)alloc(256 * 4);
    int* csr = (int*)alloc((size_t)2 * NE * 4);
    float* isq = (float*)alloc((size_t)NTOT * 4);
    float* inv = (float*)alloc((size_t)NTOT * 4);
    float* embs = (float*)alloc((size_t)NTOT * EDIM * 4);
    float* Ebuf = (float*)alloc((size_t)NTOT * EDIM * 4);
    float* gbuf = (float*)alloc((size_t)NTOT * EDIM * 4);

    // graph prep
    k_zero_int<<<(NTOT + 255) / 256, 256, 0, stream>>>(deg, NTOT);
    k_zero_int<<<1, 256, 0, stream>>>(partials, 256);
    k_count<<<(NE + 255) / 256, 256, 0, stream>>>(edge_u, edge_i, deg);
    k_blocksum<<<NBLK, 256, 0, stream>>>(deg, partials);
    k_scanpartials<<<1, 256, 0, stream>>>(partials, NBLK);
    k_scanfinal<<<NBLK, 256, 0, stream>>>(deg, partials, start, cursor);
    k_scales<<<(NTOT + 255) / 256, 256, 0, stream>>>(deg, isq, inv);
    k_fill<<<(NE + 255) / 256, 256, 0, stream>>>(edge_u, edge_i, cursor, csr);

    // embeddings init (also layer-0 term of the mean accumulator)
    k_init<<<(NTOT * EDIM / 4 + 255) / 256, 256, 0, stream>>>(u_emb, i_emb, embs, out);

    const int gatherBlocks = (NTOT * 64 + 255) / 256;   // one wave per row
    for (int l = 0; l < NLAYERS; ++l) {
        // E[n] = inv[n] * sum isqrt[m]*embs[m]
        k_gather<true><<<gatherBlocks, 256, 0, stream>>>(embs, Ebuf, csr, start, deg, inv, isq);
        // g[n] = isqrt[n] * sum E[m]
        k_gather<false><<<gatherBlocks, 256, 0, stream>>>(Ebuf, gbuf, csr, start, deg, isq, nullptr);
        float fs = (l == NLAYERS - 1) ? 0.25f : 1.0f;
        k_dense<<<2048, 64, 0, stream>>>(embs, gbuf, out, Wgc + (size_t)l * 4096,
                                         bgc + (size_t)l * 64, Wbi + (size_t)l * 4096,
                                         bbi + (size_t)l * 64, fs);
    }
}

// Round 2
// 1080.551 us; speedup vs baseline: 1.1702x; 1.1702x over previous
//
#include <hip/hip_runtime.h>
#include <cstdint>
#include <cstddef>

#define NU 100000
#define NI 50000
#define NTOT 150000
#define EDIM 64
#define NE 1000000
#define NLAYERS 3
#define SCAN_CHUNK 1024
#define NBLK ((NTOT + SCAN_CHUNK - 1) / SCAN_CHUNK)   // 147
#define FILL_PASSES 8
#define FILL_RANGE (NTOT / FILL_PASSES)               // 18750

// ---------------- bf16 helpers (raw-bit, RNE) ----------------
__device__ inline unsigned short f2bf(float f) {
    unsigned u = __float_as_uint(f);
    u += 0x7fffu + ((u >> 16) & 1u);
    return (unsigned short)(u >> 16);
}
// pack two floats into one uint: low ushort = a (lower dim), high ushort = b
__device__ inline unsigned pack_bf2(float a, float b) {
    unsigned ua = __float_as_uint(a); ua += 0x7fffu + ((ua >> 16) & 1u);
    unsigned ub = __float_as_uint(b); ub += 0x7fffu + ((ub >> 16) & 1u);
    return (ua >> 16) | (ub & 0xffff0000u);
}
__device__ inline float bf_lo(unsigned u) { return __uint_as_float(u << 16); }
__device__ inline float bf_hi(unsigned u) { return __uint_as_float(u & 0xffff0000u); }

// ---------------- utility kernels ----------------

__global__ void k_zero_int(int* __restrict__ p, int n) {
    int i = blockIdx.x * blockDim.x + threadIdx.x;
    if (i < n) p[i] = 0;
}

__global__ void k_count(const int* __restrict__ eu, const int* __restrict__ ei,
                        int* __restrict__ deg) {
    int e = blockIdx.x * blockDim.x + threadIdx.x;
    if (e < NE) {
        atomicAdd(&deg[eu[e]], 1);
        atomicAdd(&deg[NU + ei[e]], 1);
    }
}

__global__ void k_blocksum(const int* __restrict__ deg, int* __restrict__ partials) {
    __shared__ int sm[256];
    int b = blockIdx.x, t = threadIdx.x;
    int base = b * SCAN_CHUNK + t * 4;
    int s = 0;
#pragma unroll
    for (int j = 0; j < 4; ++j) {
        int idx = base + j;
        if (idx < NTOT) s += deg[idx];
    }
    sm[t] = s;
    __syncthreads();
    for (int off = 128; off > 0; off >>= 1) {
        if (t < off) sm[t] += sm[t + off];
        __syncthreads();
    }
    if (t == 0) partials[b] = sm[0];
}

__global__ void k_scanpartials(int* __restrict__ partials, int nblk) {
    __shared__ int sm[256];
    int t = threadIdx.x;
    int v = (t < nblk) ? partials[t] : 0;
    sm[t] = v;
    __syncthreads();
    for (int off = 1; off < 256; off <<= 1) {
        int tmp = (t >= off) ? sm[t - off] : 0;
        __syncthreads();
        sm[t] += tmp;
        __syncthreads();
    }
    if (t < nblk) partials[t] = sm[t] - v;   // exclusive
}

__global__ void k_scanfinal(const int* __restrict__ deg, const int* __restrict__ partials,
                            int* __restrict__ start, int* __restrict__ cursor) {
    __shared__ int sm[256];
    int b = blockIdx.x, t = threadIdx.x;
    int base = b * SCAN_CHUNK + t * 4;
    int v[4];
    int s = 0;
#pragma unroll
    for (int j = 0; j < 4; ++j) {
        int idx = base + j;
        v[j] = (idx < NTOT) ? deg[idx] : 0;
        s += v[j];
    }
    sm[t] = s;
    __syncthreads();
    for (int off = 1; off < 256; off <<= 1) {
        int tmp = (t >= off) ? sm[t - off] : 0;
        __syncthreads();
        sm[t] += tmp;
        __syncthreads();
    }
    int excl = partials[b] + sm[t] - s;
#pragma unroll
    for (int j = 0; j < 4; ++j) {
        int idx = base + j;
        if (idx < NTOT) {
            start[idx] = excl;
            cursor[idx] = excl;
            excl += v[j];
        }
    }
}

__global__ void k_scales(const int* __restrict__ deg, float* __restrict__ isq,
                         float* __restrict__ inv) {
    int i = blockIdx.x * blockDim.x + threadIdx.x;
    if (i < NTOT) {
        float d = (float)deg[i];
        isq[i] = d > 0.f ? 1.0f / sqrtf(d) : 0.f;
        inv[i] = d > 0.f ? 1.0f / d : 0.f;
    }
}

// range-filtered CSR fill: only scatter endpoints whose node id is in [lo,hi).
// The write window per pass is ~(2*NE/FILL_PASSES)*4B = 1 MB -> L2 lines
// accumulate ~16 writes before eviction (vs 1 write/line in a single pass).
__global__ void k_fill_pass(const int* __restrict__ eu, const int* __restrict__ ei,
                            int* __restrict__ cursor, int* __restrict__ csr,
                            int lo, int hi) {
    int e = blockIdx.x * blockDim.x + threadIdx.x;
    if (e < NE) {
        int u = eu[e];
        int v = NU + ei[e];
        if (u >= lo && u < hi) {
            int p = atomicAdd(&cursor[u], 1);
            csr[p] = v;
        }
        if (v >= lo && v < hi) {
            int p = atomicAdd(&cursor[v], 1);
            csr[p] = u;
        }
    }
}

// init: embs f32, out accumulator (layer-0 term), emb_bf (gather input)
__global__ void k_init(const float* __restrict__ ue, const float* __restrict__ ie,
                       float* __restrict__ embs, float* __restrict__ outacc,
                       unsigned* __restrict__ emb_bf) {
    int i = blockIdx.x * blockDim.x + threadIdx.x;
    const int n4 = NTOT * EDIM / 4;
    if (i < n4) {
        const int nu4 = NU * EDIM / 4;
        float4 v = (i < nu4) ? ((const float4*)ue)[i] : ((const float4*)ie)[i - nu4];
        ((float4*)embs)[i] = v;
        ((float4*)outacc)[i] = v;
        uint2 b;
        b.x = pack_bf2(v.x, v.y);
        b.y = pack_bf2(v.z, v.w);
        ((uint2*)emb_bf)[i] = b;
    }
}

// ---------------- sparse gather (pull), bf16 input rows ----------------
// One wave per output row. bf16 row = 128B; each 256B wave-load covers TWO
// neighbor rows (half-wave each, uint = 2 dims per lane). Lanes 0-31 accum
// even-index neighbors, 32-63 odd-index; recombined via shfl_xor(32).
// WEIGHTED: out[n] = sA[n] * sum sB[m]*in[m]; else out[n] = sA[n] * sum in[m].
template <bool WEIGHTED, bool OUTBF>
__global__ __launch_bounds__(256) void k_gather(
    const unsigned* __restrict__ in_bf, unsigned* __restrict__ out_bf,
    float* __restrict__ out_f, const int* __restrict__ csr,
    const int* __restrict__ start, const int* __restrict__ deg,
    const float* __restrict__ sA, const float* __restrict__ sB) {
    int gw = (blockIdx.x * 256 + threadIdx.x) >> 6;   // global wave = row
    int lane = threadIdx.x & 63;
    if (gw >= NTOT) return;
    int l2 = lane & 31;
    int h = lane >> 5;
    int s0 = start[gw];
    int dg = deg[gw];
    float acc0 = 0.f, acc1 = 0.f;
    for (int j0 = 0; j0 < dg; j0 += 64) {
        int lim = min(64, dg - j0);
        int nidx = 0;
        float wt = 0.f;   // lanes >= lim contribute weight 0 (row 0 read, harmless)
        if (lane < lim) {
            nidx = csr[s0 + j0 + lane];
            wt = WEIGHTED ? sB[nidx] : 1.0f;
        }
        for (int j = 0; j < lim; j += 8) {   // 4 pair-loads (8 neighbors) in flight
            int m0 = __shfl(nidx, j + h);
            int m1 = __shfl(nidx, j + 2 + h);
            int m2 = __shfl(nidx, j + 4 + h);
            int m3 = __shfl(nidx, j + 6 + h);
            float w0 = __shfl(wt, j + h);
            float w1 = __shfl(wt, j + 2 + h);
            float w2 = __shfl(wt, j + 4 + h);
            float w3 = __shfl(wt, j + 6 + h);
            unsigned u0 = in_bf[m0 * 32 + l2];
            unsigned u1 = in_bf[m1 * 32 + l2];
            unsigned u2 = in_bf[m2 * 32 + l2];
            unsigned u3 = in_bf[m3 * 32 + l2];
            acc0 += w0 * bf_lo(u0);
            acc1 += w0 * bf_hi(u0);
            acc0 += w1 * bf_lo(u1);
            acc1 += w1 * bf_hi(u1);
            acc0 += w2 * bf_lo(u2);
            acc1 += w2 * bf_hi(u2);
            acc0 += w3 * bf_lo(u3);
            acc1 += w3 * bf_hi(u3);
        }
    }
    acc0 += __shfl_xor(acc0, 32);
    acc1 += __shfl_xor(acc1, 32);
    if (lane < 32) {
        float s = sA[gw];
        if (OUTBF) {
            out_bf[gw * 32 + l2] = pack_bf2(s * acc0, s * acc1);
        } else {
            float2 o;
            o.x = s * acc0;
            o.y = s * acc1;
            ((float2*)out_f)[gw * 32 + l2] = o;
        }
    }
}

// ---------------- dense per-row update ----------------
__global__ __launch_bounds__(64) void k_dense(
    float* __restrict__ embs, const float* __restrict__ g,
    float* __restrict__ outacc, unsigned short* __restrict__ emb_bf,
    const float* __restrict__ Wg, const float* __restrict__ bg,
    const float* __restrict__ Wb, const float* __restrict__ bb, float finalScale) {
    int lane = threadIdx.x;
    float wg[64], wb[64];
#pragma unroll
    for (int k = 0; k < 64; k += 4) {
        float4 a4 = *(const float4*)&Wg[lane * 64 + k];
        wg[k] = a4.x; wg[k + 1] = a4.y; wg[k + 2] = a4.z; wg[k + 3] = a4.w;
        float4 b4 = *(const float4*)&Wb[lane * 64 + k];
        wb[k] = b4.x; wb[k + 1] = b4.y; wb[k + 2] = b4.z; wb[k + 3] = b4.w;
    }
    float bgd = bg[lane], bbd = bb[lane];
    __shared__ float gs[64];
    __shared__ float as[64];
    for (int r = blockIdx.x; r < NTOT; r += gridDim.x) {
        float a = embs[r * 64 + lane];
        float gv = g[r * 64 + lane];
        gs[lane] = gv;
        as[lane] = a * gv;
        __syncthreads();
        float s1 = 0.f, s2 = 0.f;
#pragma unroll
        for (int k = 0; k < 64; k += 4) {
            float4 g4 = *(const float4*)&gs[k];
            float4 a4 = *(const float4*)&as[k];
            s1 += g4.x * wg[k] + g4.y * wg[k + 1] + g4.z * wg[k + 2] + g4.w * wg[k + 3];
            s2 += a4.x * wb[k] + a4.y * wb[k + 1] + a4.z * wb[k + 2] + a4.w * wb[k + 3];
        }
        float e1 = s1 + bgd + a;
        e1 = e1 >= 0.f ? e1 : 0.2f * e1;
        float e2 = s2 + bbd;
        e2 = e2 >= 0.f ? e2 : 0.2f * e2;
        float nv = e1 + e2;
        float ss = nv * nv;
#pragma unroll
        for (int off = 32; off > 0; off >>= 1) ss += __shfl_xor(ss, off, 64);
        float norm = sqrtf(ss);
        float rr = nv / fmaxf(norm, 1e-12f);
        embs[r * 64 + lane] = rr;
        emb_bf[r * 64 + lane] = f2bf(rr);
        outacc[r * 64 + lane] = (outacc[r * 64 + lane] + rr) * finalScale;
        __syncthreads();
    }
}

// ---------------- launch ----------------

extern "C" void kernel_launch(void* const* d_in, const int* in_sizes, int n_in,
                              void* d_out, int out_size, void* d_ws, size_t ws_size,
                              hipStream_t stream) {
    const float* u_emb = (const float*)d_in[0];
    const float* i_emb = (const float*)d_in[1];
    const float* Wgc = (const float*)d_in[2];
    const float* bgc = (const float*)d_in[3];
    const float* Wbi = (const float*)d_in[4];
    const float* bbi = (const float*)d_in[5];
    const int* edge_u = (const int*)d_in[6];
    const int* edge_i = (const int*)d_in[7];
    float* out = (float*)d_out;

    char* w = (char*)d_ws;
    auto alloc = [&](size_t bytes) {
        char* p = w;
        w += (bytes + 255) & ~(size_t)255;
        return p;
    };
    int* deg = (int*)alloc((size_t)NTOT * 4);
    int* start = (int*)alloc((size_t)NTOT * 4);
    int* cursor = (int*)alloc((size_t)NTOT * 4);
    int* partials = (int*)alloc(256 * 4);
    int* csr = (int*)alloc((size_t)2 * NE * 4);
    float* isq = (float*)alloc((size_t)NTOT * 4);
    float* inv = (float*)alloc((size_t)NTOT * 4);
    float* embs = (float*)alloc((size_t)NTOT * EDIM * 4);
    float* gbuf = (float*)alloc((size_t)NTOT * EDIM * 4);
    unsigned* emb_bf = (unsigned*)alloc((size_t)NTOT * EDIM * 2);
    unsigned* E_bf = (unsigned*)alloc((size_t)NTOT * EDIM * 2);

    // graph prep
    k_zero_int<<<(NTOT + 255) / 256, 256, 0, stream>>>(deg, NTOT);
    k_zero_int<<<1, 256, 0, stream>>>(partials, 256);
    k_count<<<(NE + 255) / 256, 256, 0, stream>>>(edge_u, edge_i, deg);
    k_blocksum<<<NBLK, 256, 0, stream>>>(deg, partials);
    k_scanpartials<<<1, 256, 0, stream>>>(partials, NBLK);
    k_scanfinal<<<NBLK, 256, 0, stream>>>(deg, partials, start, cursor);
    k_scales<<<(NTOT + 255) / 256, 256, 0, stream>>>(deg, isq, inv);
    for (int p = 0; p < FILL_PASSES; ++p) {
        k_fill_pass<<<(NE + 255) / 256, 256, 0, stream>>>(
            edge_u, edge_i, cursor, csr, p * FILL_RANGE, (p + 1) * FILL_RANGE);
    }

    k_init<<<(NTOT * EDIM / 4 + 255) / 256, 256, 0, stream>>>(u_emb, i_emb, embs, out, emb_bf);

    const int gatherBlocks = (NTOT * 64 + 255) / 256;   // one wave per row
    for (int l = 0; l < NLAYERS; ++l) {
        // E[n] = inv[n] * sum isqrt[m]*embs[m]   (bf16 in, bf16 out)
        k_gather<true, true><<<gatherBlocks, 256, 0, stream>>>(
            emb_bf, E_bf, nullptr, csr, start, deg, inv, isq);
        // g[n] = isqrt[n] * sum E[m]             (bf16 in, f32 out)
        k_gather<false, false><<<gatherBlocks, 256, 0, stream>>>(
            E_bf, nullptr, gbuf, csr, start, deg, isq, nullptr);
        float fs = (l == NLAYERS - 1) ? 0.25f : 1.0f;
        k_dense<<<2048, 64, 0, stream>>>(embs, gbuf, out, (unsigned short*)emb_bf,
                                         Wgc + (size_t)l * 4096, bgc + (size_t)l * 64,
                                         Wbi + (size_t)l * 4096, bbi + (size_t)l * 64, fs);
    }
}

// Round 3
// 866.039 us; speedup vs baseline: 1.4600x; 1.2477x over previous
//
#include <hip/hip_runtime.h>
#include <cstdint>
#include <cstddef>

#define NU 100000
#define NI 50000
#define NTOT 150000
#define EDIM 64
#define NE 1000000
#define NLAYERS 3
#define SCAN_CHUNK 1024
#define NBLK ((NTOT + SCAN_CHUNK - 1) / SCAN_CHUNK)   // 147
#define FILL_PASSES 8
#define FILL_RANGE (NTOT / FILL_PASSES)               // 18750
#define NTILES (NTOT / 16)                            // 9375

typedef __attribute__((ext_vector_type(8))) short short8;   // 8 bf16 (4 VGPRs)
typedef __attribute__((ext_vector_type(4))) float floatx4;  // 4 fp32 acc

// ---------------- bf16 helpers (raw-bit, RNE) ----------------
__device__ inline unsigned short f2bf(float f) {
    unsigned u = __float_as_uint(f);
    u += 0x7fffu + ((u >> 16) & 1u);
    return (unsigned short)(u >> 16);
}
__device__ inline unsigned pack_bf2(float a, float b) {
    unsigned ua = __float_as_uint(a); ua += 0x7fffu + ((ua >> 16) & 1u);
    unsigned ub = __float_as_uint(b); ub += 0x7fffu + ((ub >> 16) & 1u);
    return (ua >> 16) | (ub & 0xffff0000u);
}
__device__ inline float bf_lo(unsigned u) { return __uint_as_float(u << 16); }
__device__ inline float bf_hi(unsigned u) { return __uint_as_float(u & 0xffff0000u); }

// ---------------- utility kernels ----------------

__global__ void k_zero_int(int* __restrict__ p, int n) {
    int i = blockIdx.x * blockDim.x + threadIdx.x;
    if (i < n) p[i] = 0;
}

__global__ void k_count(const int* __restrict__ eu, const int* __restrict__ ei,
                        int* __restrict__ deg) {
    int e = blockIdx.x * blockDim.x + threadIdx.x;
    if (e < NE) {
        atomicAdd(&deg[eu[e]], 1);
        atomicAdd(&deg[NU + ei[e]], 1);
    }
}

__global__ void k_blocksum(const int* __restrict__ deg, int* __restrict__ partials) {
    __shared__ int sm[256];
    int b = blockIdx.x, t = threadIdx.x;
    int base = b * SCAN_CHUNK + t * 4;
    int s = 0;
#pragma unroll
    for (int j = 0; j < 4; ++j) {
        int idx = base + j;
        if (idx < NTOT) s += deg[idx];
    }
    sm[t] = s;
    __syncthreads();
    for (int off = 128; off > 0; off >>= 1) {
        if (t < off) sm[t] += sm[t + off];
        __syncthreads();
    }
    if (t == 0) partials[b] = sm[0];
}

__global__ void k_scanpartials(int* __restrict__ partials, int nblk) {
    __shared__ int sm[256];
    int t = threadIdx.x;
    int v = (t < nblk) ? partials[t] : 0;
    sm[t] = v;
    __syncthreads();
    for (int off = 1; off < 256; off <<= 1) {
        int tmp = (t >= off) ? sm[t - off] : 0;
        __syncthreads();
        sm[t] += tmp;
        __syncthreads();
    }
    if (t < nblk) partials[t] = sm[t] - v;   // exclusive
}

__global__ void k_scanfinal(const int* __restrict__ deg, const int* __restrict__ partials,
                            int* __restrict__ start, int* __restrict__ cursor) {
    __shared__ int sm[256];
    int b = blockIdx.x, t = threadIdx.x;
    int base = b * SCAN_CHUNK + t * 4;
    int v[4];
    int s = 0;
#pragma unroll
    for (int j = 0; j < 4; ++j) {
        int idx = base + j;
        v[j] = (idx < NTOT) ? deg[idx] : 0;
        s += v[j];
    }
    sm[t] = s;
    __syncthreads();
    for (int off = 1; off < 256; off <<= 1) {
        int tmp = (t >= off) ? sm[t - off] : 0;
        __syncthreads();
        sm[t] += tmp;
        __syncthreads();
    }
    int excl = partials[b] + sm[t] - s;
#pragma unroll
    for (int j = 0; j < 4; ++j) {
        int idx = base + j;
        if (idx < NTOT) {
            start[idx] = excl;
            cursor[idx] = excl;
            excl += v[j];
        }
    }
}

__global__ void k_scales(const int* __restrict__ deg, float* __restrict__ isq,
                         float* __restrict__ inv) {
    int i = blockIdx.x * blockDim.x + threadIdx.x;
    if (i < NTOT) {
        float d = (float)deg[i];
        isq[i] = d > 0.f ? 1.0f / sqrtf(d) : 0.f;
        inv[i] = d > 0.f ? 1.0f / d : 0.f;
    }
}

// range-filtered CSR fill (keeps the write window ~1 MB/pass -> L2-resident)
__global__ void k_fill_pass(const int* __restrict__ eu, const int* __restrict__ ei,
                            int* __restrict__ cursor, int* __restrict__ csr,
                            int lo, int hi) {
    int e = blockIdx.x * blockDim.x + threadIdx.x;
    if (e < NE) {
        int u = eu[e];
        int v = NU + ei[e];
        if (u >= lo && u < hi) {
            int p = atomicAdd(&cursor[u], 1);
            csr[p] = v;
        }
        if (v >= lo && v < hi) {
            int p = atomicAdd(&cursor[v], 1);
            csr[p] = u;
        }
    }
}

__global__ void k_init(const float* __restrict__ ue, const float* __restrict__ ie,
                       float* __restrict__ embs, float* __restrict__ outacc,
                       unsigned* __restrict__ emb_bf) {
    int i = blockIdx.x * blockDim.x + threadIdx.x;
    const int n4 = NTOT * EDIM / 4;
    if (i < n4) {
        const int nu4 = NU * EDIM / 4;
        float4 v = (i < nu4) ? ((const float4*)ue)[i] : ((const float4*)ie)[i - nu4];
        ((float4*)embs)[i] = v;
        ((float4*)outacc)[i] = v;
        uint2 b;
        b.x = pack_bf2(v.x, v.y);
        b.y = pack_bf2(v.z, v.w);
        ((uint2*)emb_bf)[i] = b;
    }
}

// ---------------- sparse gather (pull), bf16 input rows ----------------
template <bool WEIGHTED, bool OUTBF>
__global__ __launch_bounds__(256) void k_gather(
    const unsigned* __restrict__ in_bf, unsigned* __restrict__ out_bf,
    float* __restrict__ out_f, const int* __restrict__ csr,
    const int* __restrict__ start, const int* __restrict__ deg,
    const float* __restrict__ sA, const float* __restrict__ sB) {
    int gw = (blockIdx.x * 256 + threadIdx.x) >> 6;   // global wave = row
    int lane = threadIdx.x & 63;
    if (gw >= NTOT) return;
    int l2 = lane & 31;
    int h = lane >> 5;
    int s0 = start[gw];
    int dg = deg[gw];
    float acc0 = 0.f, acc1 = 0.f;
    for (int j0 = 0; j0 < dg; j0 += 64) {
        int lim = min(64, dg - j0);
        int nidx = 0;
        float wt = 0.f;   // lanes >= lim contribute weight 0
        if (lane < lim) {
            nidx = csr[s0 + j0 + lane];
            wt = WEIGHTED ? sB[nidx] : 1.0f;
        }
        for (int j = 0; j < lim; j += 8) {
            int m0 = __shfl(nidx, j + h);
            int m1 = __shfl(nidx, j + 2 + h);
            int m2 = __shfl(nidx, j + 4 + h);
            int m3 = __shfl(nidx, j + 6 + h);
            float w0 = __shfl(wt, j + h);
            float w1 = __shfl(wt, j + 2 + h);
            float w2 = __shfl(wt, j + 4 + h);
            float w3 = __shfl(wt, j + 6 + h);
            unsigned u0 = in_bf[m0 * 32 + l2];
            unsigned u1 = in_bf[m1 * 32 + l2];
            unsigned u2 = in_bf[m2 * 32 + l2];
            unsigned u3 = in_bf[m3 * 32 + l2];
            acc0 += w0 * bf_lo(u0);
            acc1 += w0 * bf_hi(u0);
            acc0 += w1 * bf_lo(u1);
            acc1 += w1 * bf_hi(u1);
            acc0 += w2 * bf_lo(u2);
            acc1 += w2 * bf_hi(u2);
            acc0 += w3 * bf_lo(u3);
            acc1 += w3 * bf_hi(u3);
        }
    }
    acc0 += __shfl_xor(acc0, 32);
    acc1 += __shfl_xor(acc1, 32);
    if (lane < 32) {
        float s = sA[gw];
        if (OUTBF) {
            out_bf[gw * 32 + l2] = pack_bf2(s * acc0, s * acc1);
        } else {
            float2 o;
            o.x = s * acc0;
            o.y = s * acc1;
            ((float2*)out_f)[gw * 32 + l2] = o;
        }
    }
}

// ---------------- dense per-row update via MFMA ----------------
// One wave per 16-row tile. C = leaky(g@Wg^T + bg + a) + leaky((a*g)@Wb^T + bb),
// then row-L2-normalize, store embs(f32)+emb_bf(bf16), accumulate outacc.
// A-frag layout (16x16x32): A[m=lane&15][k=quad*8+j]; B[k][n=lane&15][k=quad*8+j];
// C/D: col=lane&15, row=quad*4+reg.
__global__ __launch_bounds__(256) void k_dense_mfma(
    float* __restrict__ embs, const unsigned* __restrict__ g_bf,
    float* __restrict__ outacc, unsigned short* __restrict__ emb_bf,
    const float* __restrict__ Wg, const float* __restrict__ bg,
    const float* __restrict__ Wb, const float* __restrict__ bb, float finalScale) {
    int lane = threadIdx.x & 63;
    int lanelo = lane & 15;
    int quad = lane >> 4;
    int wid = (blockIdx.x * blockDim.x + threadIdx.x) >> 6;
    int nw = (gridDim.x * blockDim.x) >> 6;

    // --- loop-invariant B-fragments for both W matrices (bf16, registers) ---
    short8 bWg[4][2], bWb[4][2];
#pragma unroll
    for (int t = 0; t < 4; ++t) {
#pragma unroll
        for (int h = 0; h < 2; ++h) {
            int n = t * 16 + lanelo;
            int k0 = h * 32 + quad * 8;
            const float* pg = &Wg[n * 64 + k0];
            const float* pb = &Wb[n * 64 + k0];
            short8 sg, sb;
#pragma unroll
            for (int j = 0; j < 8; ++j) {
                sg[j] = (short)f2bf(pg[j]);
                sb[j] = (short)f2bf(pb[j]);
            }
            bWg[t][h] = sg;
            bWb[t][h] = sb;
        }
    }
    float bgv[4], bbv[4];
#pragma unroll
    for (int t = 0; t < 4; ++t) {
        bgv[t] = bg[t * 16 + lanelo];
        bbv[t] = bb[t * 16 + lanelo];
    }

    for (int tile = wid; tile < NTILES; tile += nw) {
        int rbase = tile * 16;
        // --- A-fragments: g rows and (a*g) rows, bf16 ---
        int arow = rbase + lanelo;
        short8 aG[2], aAG[2];
#pragma unroll
        for (int h = 0; h < 2; ++h) {
            const uint4* pgr = (const uint4*)&g_bf[arow * 32 + h * 16 + quad * 4];
            const uint4* par = (const uint4*)((const unsigned*)emb_bf + arow * 32 + h * 16 + quad * 4);
            uint4 ug = *pgr;
            uint4 ua = *par;
            aG[h] = *(const short8*)&ug;
            uint4 up;
            up.x = pack_bf2(bf_lo(ua.x) * bf_lo(ug.x), bf_hi(ua.x) * bf_hi(ug.x));
            up.y = pack_bf2(bf_lo(ua.y) * bf_lo(ug.y), bf_hi(ua.y) * bf_hi(ug.y));
            up.z = pack_bf2(bf_lo(ua.z) * bf_lo(ug.z), bf_hi(ua.z) * bf_hi(ug.z));
            up.w = pack_bf2(bf_lo(ua.w) * bf_lo(ug.w), bf_hi(ua.w) * bf_hi(ug.w));
            aAG[h] = *(const short8*)&up;
        }
        // --- MFMA: 4 col-tiles x 2 k-halves x 2 matmuls ---
        floatx4 accg[4], accb[4];
#pragma unroll
        for (int t = 0; t < 4; ++t) {
            accg[t] = (floatx4)(0.f);
            accb[t] = (floatx4)(0.f);
        }
#pragma unroll
        for (int t = 0; t < 4; ++t) {
#pragma unroll
            for (int h = 0; h < 2; ++h) {
                accg[t] = __builtin_amdgcn_mfma_f32_16x16x32_bf16(aG[h], bWg[t][h], accg[t], 0, 0, 0);
                accb[t] = __builtin_amdgcn_mfma_f32_16x16x32_bf16(aAG[h], bWb[t][h], accb[t], 0, 0, 0);
            }
        }
        // --- epilogue in C/D layout: row = rbase + quad*4 + i, col = t*16+lanelo
        float nv[4][4];
        float ss[4] = {0.f, 0.f, 0.f, 0.f};
#pragma unroll
        for (int i = 0; i < 4; ++i) {
            int r = rbase + quad * 4 + i;
#pragma unroll
            for (int t = 0; t < 4; ++t) {
                float a = embs[r * 64 + t * 16 + lanelo];
                float e1 = accg[t][i] + bgv[t] + a;
                e1 = e1 >= 0.f ? e1 : 0.2f * e1;
                float e2 = accb[t][i] + bbv[t];
                e2 = e2 >= 0.f ? e2 : 0.2f * e2;
                float v = e1 + e2;
                nv[i][t] = v;
                ss[i] += v * v;
            }
        }
#pragma unroll
        for (int m = 1; m < 16; m <<= 1) {
#pragma unroll
            for (int i = 0; i < 4; ++i) ss[i] += __shfl_xor(ss[i], m, 64);
        }
#pragma unroll
        for (int i = 0; i < 4; ++i) {
            int r = rbase + quad * 4 + i;
            float rn = 1.0f / fmaxf(sqrtf(ss[i]), 1e-12f);
#pragma unroll
            for (int t = 0; t < 4; ++t) {
                int idx = r * 64 + t * 16 + lanelo;
                float rr = nv[i][t] * rn;
                embs[idx] = rr;
                emb_bf[idx] = f2bf(rr);
                outacc[idx] = (outacc[idx] + rr) * finalScale;
            }
        }
    }
}

// ---------------- launch ----------------

extern "C" void kernel_launch(void* const* d_in, const int* in_sizes, int n_in,
                              void* d_out, int out_size, void* d_ws, size_t ws_size,
                              hipStream_t stream) {
    const float* u_emb = (const float*)d_in[0];
    const float* i_emb = (const float*)d_in[1];
    const float* Wgc = (const float*)d_in[2];
    const float* bgc = (const float*)d_in[3];
    const float* Wbi = (const float*)d_in[4];
    const float* bbi = (const float*)d_in[5];
    const int* edge_u = (const int*)d_in[6];
    const int* edge_i = (const int*)d_in[7];
    float* out = (float*)d_out;

    char* w = (char*)d_ws;
    auto alloc = [&](size_t bytes) {
        char* p = w;
        w += (bytes + 255) & ~(size_t)255;
        return p;
    };
    int* deg = (int*)alloc((size_t)NTOT * 4);
    int* start = (int*)alloc((size_t)NTOT * 4);
    int* cursor = (int*)alloc((size_t)NTOT * 4);
    int* partials = (int*)alloc(256 * 4);
    int* csr = (int*)alloc((size_t)2 * NE * 4);
    float* isq = (float*)alloc((size_t)NTOT * 4);
    float* inv = (float*)alloc((size_t)NTOT * 4);
    float* embs = (float*)alloc((size_t)NTOT * EDIM * 4);
    unsigned* emb_bf = (unsigned*)alloc((size_t)NTOT * EDIM * 2);
    unsigned* E_bf = (unsigned*)alloc((size_t)NTOT * EDIM * 2);
    unsigned* g_bf = (unsigned*)alloc((size_t)NTOT * EDIM * 2);

    // graph prep
    k_zero_int<<<(NTOT + 255) / 256, 256, 0, stream>>>(deg, NTOT);
    k_zero_int<<<1, 256, 0, stream>>>(partials, 256);
    k_count<<<(NE + 255) / 256, 256, 0, stream>>>(edge_u, edge_i, deg);
    k_blocksum<<<NBLK, 256, 0, stream>>>(deg, partials);
    k_scanpartials<<<1, 256, 0, stream>>>(partials, NBLK);
    k_scanfinal<<<NBLK, 256, 0, stream>>>(deg, partials, start, cursor);
    k_scales<<<(NTOT + 255) / 256, 256, 0, stream>>>(deg, isq, inv);
    for (int p = 0; p < FILL_PASSES; ++p) {
        k_fill_pass<<<(NE + 255) / 256, 256, 0, stream>>>(
            edge_u, edge_i, cursor, csr, p * FILL_RANGE, (p + 1) * FILL_RANGE);
    }

    k_init<<<(NTOT * EDIM / 4 + 255) / 256, 256, 0, stream>>>(u_emb, i_emb, embs, out, emb_bf);

    const int gatherBlocks = (NTOT * 64 + 255) / 256;   // one wave per row
    for (int l = 0; l < NLAYERS; ++l) {
        // E[n] = inv[n] * sum isqrt[m]*embs[m]   (bf16 in, bf16 out)
        k_gather<true, true><<<gatherBlocks, 256, 0, stream>>>(
            emb_bf, E_bf, nullptr, csr, start, deg, inv, isq);
        // g[n] = isqrt[n] * sum E[m]             (bf16 in, bf16 out)
        k_gather<false, true><<<gatherBlocks, 256, 0, stream>>>(
            E_bf, g_bf, nullptr, csr, start, deg, isq, nullptr);
        float fs = (l == NLAYERS - 1) ? 0.25f : 1.0f;
        k_dense_mfma<<<1024, 256, 0, stream>>>(
            embs, g_bf, out, (unsigned short*)emb_bf,
            Wgc + (size_t)l * 4096, bgc + (size_t)l * 64,
            Wbi + (size_t)l * 4096, bbi + (size_t)l * 64, fs);
    }
}

// Round 4
// 853.871 us; speedup vs baseline: 1.4808x; 1.0143x over previous
//
#include <hip/hip_runtime.h>
#include <cstdint>
#include <cstddef>

#define NU 100000
#define NI 50000
#define NTOT 150000
#define EDIM 64
#define NE 1000000
#define NLAYERS 3
#define SCAN_CHUNK 1024
#define NBLK ((NTOT + SCAN_CHUNK - 1) / SCAN_CHUNK)   // 147
#define FILL_PASSES 8
#define FILL_RANGE (NTOT / FILL_PASSES)               // 18750
#define NTILES (NTOT / 16)                            // 9375

// histogram config: 11 ranges x 16 slices; 15360 bins = 60KB LDS (<64KB cap)
#define RBINS 15360
#define NSLICE 16
#define NRANGE_U 7
#define NRANGE_I 4
#define NRANGE (NRANGE_U + NRANGE_I)

typedef __attribute__((ext_vector_type(8))) short short8;   // 8 bf16 (4 VGPRs)
typedef __attribute__((ext_vector_type(4))) float floatx4;  // 4 fp32 acc

// ---------------- bf16 helpers (raw-bit, RNE) ----------------
__device__ inline unsigned short f2bf(float f) {
    unsigned u = __float_as_uint(f);
    u += 0x7fffu + ((u >> 16) & 1u);
    return (unsigned short)(u >> 16);
}
__device__ inline unsigned pack_bf2(float a, float b) {
    unsigned ua = __float_as_uint(a); ua += 0x7fffu + ((ua >> 16) & 1u);
    unsigned ub = __float_as_uint(b); ub += 0x7fffu + ((ub >> 16) & 1u);
    return (ua >> 16) | (ub & 0xffff0000u);
}
__device__ inline float bf_lo(unsigned u) { return __uint_as_float(u << 16); }
__device__ inline float bf_hi(unsigned u) { return __uint_as_float(u & 0xffff0000u); }

// ---------------- degree histogram (no global atomics) ----------------
// block = (range r, slice s). LDS-private histogram of node ids in
// [base, base+RBINS) over edge slice s, flushed coalesced to partial[s].
__global__ __launch_bounds__(256) void k_hist(const int* __restrict__ eu,
                                              const int* __restrict__ ei,
                                              int* __restrict__ partial) {
    __shared__ int h[RBINS];
    int r = blockIdx.x / NSLICE;
    int s = blockIdx.x % NSLICE;
    const int* arr;
    int base, node_off, nnode;
    if (r < NRANGE_U) {
        arr = eu; base = r * RBINS; node_off = 0; nnode = NU;
    } else {
        arr = ei; base = (r - NRANGE_U) * RBINS; node_off = NU; nnode = NI;
    }
    for (int i = threadIdx.x; i < RBINS; i += 256) h[i] = 0;
    __syncthreads();
    const int e0 = s * (NE / NSLICE), e1 = e0 + NE / NSLICE;
    for (int e = e0 + threadIdx.x; e < e1; e += 256) {
        unsigned local = (unsigned)(arr[e] - base);
        if (local < (unsigned)RBINS) atomicAdd(&h[local], 1);
    }
    __syncthreads();
    int lim = min(RBINS, nnode - base);
    for (int i = threadIdx.x; i < lim; i += 256) {
        partial[s * NTOT + node_off + base + i] = h[i];
    }
}

// merge partials -> deg, and fuse the scale computation
__global__ void k_merge(const int* __restrict__ partial, int* __restrict__ deg,
                        float* __restrict__ isq, float* __restrict__ inv) {
    int n = blockIdx.x * blockDim.x + threadIdx.x;
    if (n < NTOT) {
        int d = 0;
#pragma unroll
        for (int s = 0; s < NSLICE; ++s) d += partial[s * NTOT + n];
        deg[n] = d;
        float df = (float)d;
        isq[n] = d > 0 ? 1.0f / sqrtf(df) : 0.f;
        inv[n] = d > 0 ? 1.0f / df : 0.f;
    }
}

// ---------------- scan kernels ----------------

__global__ void k_blocksum(const int* __restrict__ deg, int* __restrict__ partials) {
    __shared__ int sm[256];
    int b = blockIdx.x, t = threadIdx.x;
    int base = b * SCAN_CHUNK + t * 4;
    int s = 0;
#pragma unroll
    for (int j = 0; j < 4; ++j) {
        int idx = base + j;
        if (idx < NTOT) s += deg[idx];
    }
    sm[t] = s;
    __syncthreads();
    for (int off = 128; off > 0; off >>= 1) {
        if (t < off) sm[t] += sm[t + off];
        __syncthreads();
    }
    if (t == 0) partials[b] = sm[0];
}

__global__ void k_scanpartials(int* __restrict__ partials, int nblk) {
    __shared__ int sm[256];
    int t = threadIdx.x;
    int v = (t < nblk) ? partials[t] : 0;
    sm[t] = v;
    __syncthreads();
    for (int off = 1; off < 256; off <<= 1) {
        int tmp = (t >= off) ? sm[t - off] : 0;
        __syncthreads();
        sm[t] += tmp;
        __syncthreads();
    }
    if (t < nblk) partials[t] = sm[t] - v;   // exclusive
}

__global__ void k_scanfinal(const int* __restrict__ deg, const int* __restrict__ partials,
                            int* __restrict__ start, int* __restrict__ cursor) {
    __shared__ int sm[256];
    int b = blockIdx.x, t = threadIdx.x;
    int base = b * SCAN_CHUNK + t * 4;
    int v[4];
    int s = 0;
#pragma unroll
    for (int j = 0; j < 4; ++j) {
        int idx = base + j;
        v[j] = (idx < NTOT) ? deg[idx] : 0;
        s += v[j];
    }
    sm[t] = s;
    __syncthreads();
    for (int off = 1; off < 256; off <<= 1) {
        int tmp = (t >= off) ? sm[t - off] : 0;
        __syncthreads();
        sm[t] += tmp;
        __syncthreads();
    }
    int excl = partials[b] + sm[t] - s;
#pragma unroll
    for (int j = 0; j < 4; ++j) {
        int idx = base + j;
        if (idx < NTOT) {
            start[idx] = excl;
            cursor[idx] = excl;
            excl += v[j];
        }
    }
}

// range-filtered CSR fill (keeps the write window ~1 MB/pass -> L2-resident)
__global__ void k_fill_pass(const int* __restrict__ eu, const int* __restrict__ ei,
                            int* __restrict__ cursor, int* __restrict__ csr,
                            int lo, int hi) {
    int e = blockIdx.x * blockDim.x + threadIdx.x;
    if (e < NE) {
        int u = eu[e];
        int v = NU + ei[e];
        if (u >= lo && u < hi) {
            int p = atomicAdd(&cursor[u], 1);
            csr[p] = v;
        }
        if (v >= lo && v < hi) {
            int p = atomicAdd(&cursor[v], 1);
            csr[p] = u;
        }
    }
}

__global__ void k_init(const float* __restrict__ ue, const float* __restrict__ ie,
                       float* __restrict__ embs, float* __restrict__ outacc,
                       unsigned* __restrict__ emb_bf) {
    int i = blockIdx.x * blockDim.x + threadIdx.x;
    const int n4 = NTOT * EDIM / 4;
    if (i < n4) {
        const int nu4 = NU * EDIM / 4;
        float4 v = (i < nu4) ? ((const float4*)ue)[i] : ((const float4*)ie)[i - nu4];
        ((float4*)embs)[i] = v;
        ((float4*)outacc)[i] = v;
        uint2 b;
        b.x = pack_bf2(v.x, v.y);
        b.y = pack_bf2(v.z, v.w);
        ((uint2*)emb_bf)[i] = b;
    }
}

// ---------------- sparse gather (pull), bf16 input rows ----------------
template <bool WEIGHTED, bool OUTBF>
__global__ __launch_bounds__(256) void k_gather(
    const unsigned* __restrict__ in_bf, unsigned* __restrict__ out_bf,
    float* __restrict__ out_f, const int* __restrict__ csr,
    const int* __restrict__ start, const int* __restrict__ deg,
    const float* __restrict__ sA, const float* __restrict__ sB) {
    int gw = (blockIdx.x * 256 + threadIdx.x) >> 6;   // global wave = row
    int lane = threadIdx.x & 63;
    if (gw >= NTOT) return;
    int l2 = lane & 31;
    int h = lane >> 5;
    int s0 = start[gw];
    int dg = deg[gw];
    float acc0 = 0.f, acc1 = 0.f;
    for (int j0 = 0; j0 < dg; j0 += 64) {
        int lim = min(64, dg - j0);
        int nidx = 0;
        float wt = 0.f;   // lanes >= lim contribute weight 0
        if (lane < lim) {
            nidx = csr[s0 + j0 + lane];
            wt = WEIGHTED ? sB[nidx] : 1.0f;
        }
        for (int j = 0; j < lim; j += 8) {
            int m0 = __shfl(nidx, j + h);
            int m1 = __shfl(nidx, j + 2 + h);
            int m2 = __shfl(nidx, j + 4 + h);
            int m3 = __shfl(nidx, j + 6 + h);
            float w0 = __shfl(wt, j + h);
            float w1 = __shfl(wt, j + 2 + h);
            float w2 = __shfl(wt, j + 4 + h);
            float w3 = __shfl(wt, j + 6 + h);
            unsigned u0 = in_bf[m0 * 32 + l2];
            unsigned u1 = in_bf[m1 * 32 + l2];
            unsigned u2 = in_bf[m2 * 32 + l2];
            unsigned u3 = in_bf[m3 * 32 + l2];
            acc0 += w0 * bf_lo(u0);
            acc1 += w0 * bf_hi(u0);
            acc0 += w1 * bf_lo(u1);
            acc1 += w1 * bf_hi(u1);
            acc0 += w2 * bf_lo(u2);
            acc1 += w2 * bf_hi(u2);
            acc0 += w3 * bf_lo(u3);
            acc1 += w3 * bf_hi(u3);
        }
    }
    acc0 += __shfl_xor(acc0, 32);
    acc1 += __shfl_xor(acc1, 32);
    if (lane < 32) {
        float s = sA[gw];
        if (OUTBF) {
            out_bf[gw * 32 + l2] = pack_bf2(s * acc0, s * acc1);
        } else {
            float2 o;
            o.x = s * acc0;
            o.y = s * acc1;
            ((float2*)out_f)[gw * 32 + l2] = o;
        }
    }
}

// ---------------- dense per-row update via MFMA ----------------
__global__ __launch_bounds__(256) void k_dense_mfma(
    float* __restrict__ embs, const unsigned* __restrict__ g_bf,
    float* __restrict__ outacc, unsigned short* __restrict__ emb_bf,
    const float* __restrict__ Wg, const float* __restrict__ bg,
    const float* __restrict__ Wb, const float* __restrict__ bb, float finalScale) {
    int lane = threadIdx.x & 63;
    int lanelo = lane & 15;
    int quad = lane >> 4;
    int wid = (blockIdx.x * blockDim.x + threadIdx.x) >> 6;
    int nw = (gridDim.x * blockDim.x) >> 6;

    short8 bWg[4][2], bWb[4][2];
#pragma unroll
    for (int t = 0; t < 4; ++t) {
#pragma unroll
        for (int h = 0; h < 2; ++h) {
            int n = t * 16 + lanelo;
            int k0 = h * 32 + quad * 8;
            const float* pg = &Wg[n * 64 + k0];
            const float* pb = &Wb[n * 64 + k0];
            short8 sg, sb;
#pragma unroll
            for (int j = 0; j < 8; ++j) {
                sg[j] = (short)f2bf(pg[j]);
                sb[j] = (short)f2bf(pb[j]);
            }
            bWg[t][h] = sg;
            bWb[t][h] = sb;
        }
    }
    float bgv[4], bbv[4];
#pragma unroll
    for (int t = 0; t < 4; ++t) {
        bgv[t] = bg[t * 16 + lanelo];
        bbv[t] = bb[t * 16 + lanelo];
    }

    for (int tile = wid; tile < NTILES; tile += nw) {
        int rbase = tile * 16;
        int arow = rbase + lanelo;
        short8 aG[2], aAG[2];
#pragma unroll
        for (int h = 0; h < 2; ++h) {
            const uint4* pgr = (const uint4*)&g_bf[arow * 32 + h * 16 + quad * 4];
            const uint4* par = (const uint4*)((const unsigned*)emb_bf + arow * 32 + h * 16 + quad * 4);
            uint4 ug = *pgr;
            uint4 ua = *par;
            aG[h] = *(const short8*)&ug;
            uint4 up;
            up.x = pack_bf2(bf_lo(ua.x) * bf_lo(ug.x), bf_hi(ua.x) * bf_hi(ug.x));
            up.y = pack_bf2(bf_lo(ua.y) * bf_lo(ug.y), bf_hi(ua.y) * bf_hi(ug.y));
            up.z = pack_bf2(bf_lo(ua.z) * bf_lo(ug.z), bf_hi(ua.z) * bf_hi(ug.z));
            up.w = pack_bf2(bf_lo(ua.w) * bf_lo(ug.w), bf_hi(ua.w) * bf_hi(ug.w));
            aAG[h] = *(const short8*)&up;
        }
        floatx4 accg[4], accb[4];
#pragma unroll
        for (int t = 0; t < 4; ++t) {
            accg[t] = (floatx4)(0.f);
            accb[t] = (floatx4)(0.f);
        }
#pragma unroll
        for (int t = 0; t < 4; ++t) {
#pragma unroll
            for (int h = 0; h < 2; ++h) {
                accg[t] = __builtin_amdgcn_mfma_f32_16x16x32_bf16(aG[h], bWg[t][h], accg[t], 0, 0, 0);
                accb[t] = __builtin_amdgcn_mfma_f32_16x16x32_bf16(aAG[h], bWb[t][h], accb[t], 0, 0, 0);
            }
        }
        float nv[4][4];
        float ss[4] = {0.f, 0.f, 0.f, 0.f};
#pragma unroll
        for (int i = 0; i < 4; ++i) {
            int r = rbase + quad * 4 + i;
#pragma unroll
            for (int t = 0; t < 4; ++t) {
                float a = embs[r * 64 + t * 16 + lanelo];
                float e1 = accg[t][i] + bgv[t] + a;
                e1 = e1 >= 0.f ? e1 : 0.2f * e1;
                float e2 = accb[t][i] + bbv[t];
                e2 = e2 >= 0.f ? e2 : 0.2f * e2;
                float v = e1 + e2;
                nv[i][t] = v;
                ss[i] += v * v;
            }
        }
#pragma unroll
        for (int m = 1; m < 16; m <<= 1) {
#pragma unroll
            for (int i = 0; i < 4; ++i) ss[i] += __shfl_xor(ss[i], m, 64);
        }
#pragma unroll
        for (int i = 0; i < 4; ++i) {
            int r = rbase + quad * 4 + i;
            float rn = 1.0f / fmaxf(sqrtf(ss[i]), 1e-12f);
#pragma unroll
            for (int t = 0; t < 4; ++t) {
                int idx = r * 64 + t * 16 + lanelo;
                float rr = nv[i][t] * rn;
                embs[idx] = rr;
                emb_bf[idx] = f2bf(rr);
                outacc[idx] = (outacc[idx] + rr) * finalScale;
            }
        }
    }
}

// ---------------- launch ----------------

extern "C" void kernel_launch(void* const* d_in, const int* in_sizes, int n_in,
                              void* d_out, int out_size, void* d_ws, size_t ws_size,
                              hipStream_t stream) {
    const float* u_emb = (const float*)d_in[0];
    const float* i_emb = (const float*)d_in[1];
    const float* Wgc = (const float*)d_in[2];
    const float* bgc = (const float*)d_in[3];
    const float* Wbi = (const float*)d_in[4];
    const float* bbi = (const float*)d_in[5];
    const int* edge_u = (const int*)d_in[6];
    const int* edge_i = (const int*)d_in[7];
    float* out = (float*)d_out;

    char* w = (char*)d_ws;
    auto alloc = [&](size_t bytes) {
        char* p = w;
        w += (bytes + 255) & ~(size_t)255;
        return p;
    };
    int* deg = (int*)alloc((size_t)NTOT * 4);
    int* start = (int*)alloc((size_t)NTOT * 4);
    int* cursor = (int*)alloc((size_t)NTOT * 4);
    int* partials = (int*)alloc(256 * 4);
    int* csr = (int*)alloc((size_t)2 * NE * 4);
    float* isq = (float*)alloc((size_t)NTOT * 4);
    float* inv = (float*)alloc((size_t)NTOT * 4);
    float* embs = (float*)alloc((size_t)NTOT * EDIM * 4);
    unsigned* emb_bf = (unsigned*)alloc((size_t)NTOT * EDIM * 2);
    unsigned* E_bf = (unsigned*)alloc((size_t)NTOT * EDIM * 2);
    unsigned* g_bf = (unsigned*)alloc((size_t)NTOT * EDIM * 2);
    // hist partials (9.6 MB) aliased onto g_bf (19.2 MB): partial is dead
    // before the first gather writes g_bf.
    int* hpartial = (int*)g_bf;

    // graph prep: degree histogram without global atomics
    k_hist<<<NRANGE * NSLICE, 256, 0, stream>>>(edge_u, edge_i, hpartial);
    k_merge<<<(NTOT + 255) / 256, 256, 0, stream>>>(hpartial, deg, isq, inv);
    k_blocksum<<<NBLK, 256, 0, stream>>>(deg, partials);
    k_scanpartials<<<1, 256, 0, stream>>>(partials, NBLK);
    k_scanfinal<<<NBLK, 256, 0, stream>>>(deg, partials, start, cursor);
    for (int p = 0; p < FILL_PASSES; ++p) {
        k_fill_pass<<<(NE + 255) / 256, 256, 0, stream>>>(
            edge_u, edge_i, cursor, csr, p * FILL_RANGE, (p + 1) * FILL_RANGE);
    }

    k_init<<<(NTOT * EDIM / 4 + 255) / 256, 256, 0, stream>>>(u_emb, i_emb, embs, out, emb_bf);

    const int gatherBlocks = (NTOT * 64 + 255) / 256;   // one wave per row
    for (int l = 0; l < NLAYERS; ++l) {
        // E[n] = inv[n] * sum isqrt[m]*embs[m]   (bf16 in, bf16 out)
        k_gather<true, true><<<gatherBlocks, 256, 0, stream>>>(
            emb_bf, E_bf, nullptr, csr, start, deg, inv, isq);
        // g[n] = isqrt[n] * sum E[m]             (bf16 in, bf16 out)
        k_gather<false, true><<<gatherBlocks, 256, 0, stream>>>(
            E_bf, g_bf, nullptr, csr, start, deg, isq, nullptr);
        float fs = (l == NLAYERS - 1) ? 0.25f : 1.0f;
        k_dense_mfma<<<1024, 256, 0, stream>>>(
            embs, g_bf, out, (unsigned short*)emb_bf,
            Wgc + (size_t)l * 4096, bgc + (size_t)l * 64,
            Wbi + (size_t)l * 4096, bbi + (size_t)l * 64, fs);
    }
}

// Round 5
// 808.990 us; speedup vs baseline: 1.5630x; 1.0555x over previous
//
#include <hip/hip_runtime.h>
#include <cstdint>
#include <cstddef>

#define NU 100000
#define NI 50000
#define NTOT 150000
#define EDIM 64
#define NE 1000000
#define NLAYERS 3
#define SCAN_CHUNK 1024
#define NBLK ((NTOT + SCAN_CHUNK - 1) / SCAN_CHUNK)   // 147
#define FILL_PASSES 8
#define FILL_RANGE (NTOT / FILL_PASSES)               // 18750
#define NTILES (NTOT / 16)                            // 9375

// byte-packed degree histogram: 4 nodes/word, 32768 nodes per 32KB block.
// 6 ranges (4 user + 2 item) x 128 edge-slices = 768 blocks, 5 blocks/CU.
#define HB_BYTES 32768
#define HB_WORDS (HB_BYTES / 4)
#define NSLICE 128
#define ESLICE ((NE + NSLICE - 1) / NSLICE)           // 7813
#define NRANGE_U 4
#define NRANGE_I 2
#define NRANGE (NRANGE_U + NRANGE_I)
#define NWORDS (NTOT / 4)                             // 37500 (NTOT%4==0)

typedef __attribute__((ext_vector_type(8))) short short8;   // 8 bf16 (4 VGPRs)
typedef __attribute__((ext_vector_type(4))) float floatx4;  // 4 fp32 acc

// ---------------- bf16 helpers (raw-bit, RNE) ----------------
__device__ inline unsigned short f2bf(float f) {
    unsigned u = __float_as_uint(f);
    u += 0x7fffu + ((u >> 16) & 1u);
    return (unsigned short)(u >> 16);
}
__device__ inline unsigned pack_bf2(float a, float b) {
    unsigned ua = __float_as_uint(a); ua += 0x7fffu + ((ua >> 16) & 1u);
    unsigned ub = __float_as_uint(b); ub += 0x7fffu + ((ub >> 16) & 1u);
    return (ua >> 16) | (ub & 0xffff0000u);
}
__device__ inline float bf_lo(unsigned u) { return __uint_as_float(u << 16); }
__device__ inline float bf_hi(unsigned u) { return __uint_as_float(u & 0xffff0000u); }

// ---------------- degree histogram, byte-packed LDS ----------------
// block = (range r, slice s). Counts node ids in a 32768-node window over
// edge slice s into byte-packed LDS (max degree << 255: no carry), then
// flushes the window coalesced into partial plane s.
__global__ __launch_bounds__(256) void k_hist(const int* __restrict__ eu,
                                              const int* __restrict__ ei,
                                              unsigned* __restrict__ partial) {
    __shared__ unsigned h[HB_WORDS];
    int r = blockIdx.x / NSLICE;
    int s = blockIdx.x % NSLICE;
    const int* arr;
    int base, gbyte, lim;
    if (r < NRANGE_U) {
        arr = eu; base = r * HB_BYTES; gbyte = base;
        lim = min(HB_BYTES, NU - base);
    } else {
        arr = ei; base = (r - NRANGE_U) * HB_BYTES; gbyte = NU + base;
        lim = min(HB_BYTES, NI - base);
    }
    for (int i = threadIdx.x; i < HB_WORDS; i += 256) h[i] = 0;
    __syncthreads();
    const int e0 = s * ESLICE, e1 = min(NE, e0 + ESLICE);
    for (int e = e0 + threadIdx.x; e < e1; e += 256) {
        unsigned local = (unsigned)(arr[e] - base);
        if (local < (unsigned)HB_BYTES)
            atomicAdd(&h[local >> 2], 1u << ((local & 3u) * 8u));
    }
    __syncthreads();
    unsigned* dst = partial + (size_t)s * NWORDS + (gbyte >> 2);
    int lw = lim >> 2;   // all range boundaries are multiples of 4
    for (int i = threadIdx.x; i < lw; i += 256) dst[i] = h[i];
}

// merge byte planes -> deg + scales. Masked 16-bit-lane adds: byte sums
// <= NSLICE*255 < 2^16, so two packed accumulators suffice.
__global__ void k_merge(const unsigned* __restrict__ partial, int* __restrict__ deg,
                        float* __restrict__ isq, float* __restrict__ inv) {
    int n = blockIdx.x * blockDim.x + threadIdx.x;
    if (n >= NWORDS) return;
    unsigned se = 0, so = 0;
    for (int s = 0; s < NSLICE; ++s) {
        unsigned v = partial[(size_t)s * NWORDS + n];
        se += v & 0x00ff00ffu;
        so += (v >> 8) & 0x00ff00ffu;
    }
    int d[4];
    d[0] = se & 0xffff; d[1] = so & 0xffff;
    d[2] = se >> 16;    d[3] = so >> 16;
    ((int4*)deg)[n] = make_int4(d[0], d[1], d[2], d[3]);
    float4 q, iv;
    float* qp = &q.x; float* ip = &iv.x;
#pragma unroll
    for (int j = 0; j < 4; ++j) {
        float df = (float)d[j];
        qp[j] = d[j] > 0 ? 1.0f / sqrtf(df) : 0.f;
        ip[j] = d[j] > 0 ? 1.0f / df : 0.f;
    }
    ((float4*)isq)[n] = q;
    ((float4*)inv)[n] = iv;
}

// ---------------- scan kernels ----------------

__global__ void k_blocksum(const int* __restrict__ deg, int* __restrict__ partials) {
    __shared__ int sm[256];
    int b = blockIdx.x, t = threadIdx.x;
    int base = b * SCAN_CHUNK + t * 4;
    int s = 0;
#pragma unroll
    for (int j = 0; j < 4; ++j) {
        int idx = base + j;
        if (idx < NTOT) s += deg[idx];
    }
    sm[t] = s;
    __syncthreads();
    for (int off = 128; off > 0; off >>= 1) {
        if (t < off) sm[t] += sm[t + off];
        __syncthreads();
    }
    if (t == 0) partials[b] = sm[0];
}

__global__ void k_scanpartials(int* __restrict__ partials, int nblk) {
    __shared__ int sm[256];
    int t = threadIdx.x;
    int v = (t < nblk) ? partials[t] : 0;
    sm[t] = v;
    __syncthreads();
    for (int off = 1; off < 256; off <<= 1) {
        int tmp = (t >= off) ? sm[t - off] : 0;
        __syncthreads();
        sm[t] += tmp;
        __syncthreads();
    }
    if (t < nblk) partials[t] = sm[t] - v;   // exclusive
}

__global__ void k_scanfinal(const int* __restrict__ deg, const int* __restrict__ partials,
                            int* __restrict__ start, int* __restrict__ cursor) {
    __shared__ int sm[256];
    int b = blockIdx.x, t = threadIdx.x;
    int base = b * SCAN_CHUNK + t * 4;
    int v[4];
    int s = 0;
#pragma unroll
    for (int j = 0; j < 4; ++j) {
        int idx = base + j;
        v[j] = (idx < NTOT) ? deg[idx] : 0;
        s += v[j];
    }
    sm[t] = s;
    __syncthreads();
    for (int off = 1; off < 256; off <<= 1) {
        int tmp = (t >= off) ? sm[t - off] : 0;
        __syncthreads();
        sm[t] += tmp;
        __syncthreads();
    }
    int excl = partials[b] + sm[t] - s;
#pragma unroll
    for (int j = 0; j < 4; ++j) {
        int idx = base + j;
        if (idx < NTOT) {
            start[idx] = excl;
            cursor[idx] = excl;
            excl += v[j];
        }
    }
}

// range-filtered CSR fill (keeps the write window ~1 MB/pass -> L2-resident)
__global__ void k_fill_pass(const int* __restrict__ eu, const int* __restrict__ ei,
                            int* __restrict__ cursor, int* __restrict__ csr,
                            int lo, int hi) {
    int e = blockIdx.x * blockDim.x + threadIdx.x;
    if (e < NE) {
        int u = eu[e];
        int v = NU + ei[e];
        if (u >= lo && u < hi) {
            int p = atomicAdd(&cursor[u], 1);
            csr[p] = v;
        }
        if (v >= lo && v < hi) {
            int p = atomicAdd(&cursor[v], 1);
            csr[p] = u;
        }
    }
}

__global__ void k_init(const float* __restrict__ ue, const float* __restrict__ ie,
                       float* __restrict__ embs, float* __restrict__ outacc,
                       unsigned* __restrict__ emb_bf) {
    int i = blockIdx.x * blockDim.x + threadIdx.x;
    const int n4 = NTOT * EDIM / 4;
    if (i < n4) {
        const int nu4 = NU * EDIM / 4;
        float4 v = (i < nu4) ? ((const float4*)ue)[i] : ((const float4*)ie)[i - nu4];
        ((float4*)embs)[i] = v;
        ((float4*)outacc)[i] = v;
        uint2 b;
        b.x = pack_bf2(v.x, v.y);
        b.y = pack_bf2(v.z, v.w);
        ((uint2*)emb_bf)[i] = b;
    }
}

// ---------------- sparse gather (pull), bf16 input rows ----------------
template <bool WEIGHTED, bool OUTBF>
__global__ __launch_bounds__(256) void k_gather(
    const unsigned* __restrict__ in_bf, unsigned* __restrict__ out_bf,
    float* __restrict__ out_f, const int* __restrict__ csr,
    const int* __restrict__ start, const int* __restrict__ deg,
    const float* __restrict__ sA, const float* __restrict__ sB) {
    int gw = (blockIdx.x * 256 + threadIdx.x) >> 6;   // global wave = row
    int lane = threadIdx.x & 63;
    if (gw >= NTOT) return;
    int l2 = lane & 31;
    int h = lane >> 5;
    int s0 = start[gw];
    int dg = deg[gw];
    float acc0 = 0.f, acc1 = 0.f;
    for (int j0 = 0; j0 < dg; j0 += 64) {
        int lim = min(64, dg - j0);
        int nidx = 0;
        float wt = 0.f;   // lanes >= lim contribute weight 0
        if (lane < lim) {
            nidx = csr[s0 + j0 + lane];
            wt = WEIGHTED ? sB[nidx] : 1.0f;
        }
        for (int j = 0; j < lim; j += 8) {
            int m0 = __shfl(nidx, j + h);
            int m1 = __shfl(nidx, j + 2 + h);
            int m2 = __shfl(nidx, j + 4 + h);
            int m3 = __shfl(nidx, j + 6 + h);
            float w0 = __shfl(wt, j + h);
            float w1 = __shfl(wt, j + 2 + h);
            float w2 = __shfl(wt, j + 4 + h);
            float w3 = __shfl(wt, j + 6 + h);
            unsigned u0 = in_bf[m0 * 32 + l2];
            unsigned u1 = in_bf[m1 * 32 + l2];
            unsigned u2 = in_bf[m2 * 32 + l2];
            unsigned u3 = in_bf[m3 * 32 + l2];
            acc0 += w0 * bf_lo(u0);
            acc1 += w0 * bf_hi(u0);
            acc0 += w1 * bf_lo(u1);
            acc1 += w1 * bf_hi(u1);
            acc0 += w2 * bf_lo(u2);
            acc1 += w2 * bf_hi(u2);
            acc0 += w3 * bf_lo(u3);
            acc1 += w3 * bf_hi(u3);
        }
    }
    acc0 += __shfl_xor(acc0, 32);
    acc1 += __shfl_xor(acc1, 32);
    if (lane < 32) {
        float s = sA[gw];
        if (OUTBF) {
            out_bf[gw * 32 + l2] = pack_bf2(s * acc0, s * acc1);
        } else {
            float2 o;
            o.x = s * acc0;
            o.y = s * acc1;
            ((float2*)out_f)[gw * 32 + l2] = o;
        }
    }
}

// ---------------- dense per-row update via MFMA ----------------
__global__ __launch_bounds__(256) void k_dense_mfma(
    float* __restrict__ embs, const unsigned* __restrict__ g_bf,
    float* __restrict__ outacc, unsigned short* __restrict__ emb_bf,
    const float* __restrict__ Wg, const float* __restrict__ bg,
    const float* __restrict__ Wb, const float* __restrict__ bb, float finalScale) {
    int lane = threadIdx.x & 63;
    int lanelo = lane & 15;
    int quad = lane >> 4;
    int wid = (blockIdx.x * blockDim.x + threadIdx.x) >> 6;
    int nw = (gridDim.x * blockDim.x) >> 6;

    short8 bWg[4][2], bWb[4][2];
#pragma unroll
    for (int t = 0; t < 4; ++t) {
#pragma unroll
        for (int h = 0; h < 2; ++h) {
            int n = t * 16 + lanelo;
            int k0 = h * 32 + quad * 8;
            const float* pg = &Wg[n * 64 + k0];
            const float* pb = &Wb[n * 64 + k0];
            short8 sg, sb;
#pragma unroll
            for (int j = 0; j < 8; ++j) {
                sg[j] = (short)f2bf(pg[j]);
                sb[j] = (short)f2bf(pb[j]);
            }
            bWg[t][h] = sg;
            bWb[t][h] = sb;
        }
    }
    float bgv[4], bbv[4];
#pragma unroll
    for (int t = 0; t < 4; ++t) {
        bgv[t] = bg[t * 16 + lanelo];
        bbv[t] = bb[t * 16 + lanelo];
    }

    for (int tile = wid; tile < NTILES; tile += nw) {
        int rbase = tile * 16;
        int arow = rbase + lanelo;
        short8 aG[2], aAG[2];
#pragma unroll
        for (int h = 0; h < 2; ++h) {
            const uint4* pgr = (const uint4*)&g_bf[arow * 32 + h * 16 + quad * 4];
            const uint4* par = (const uint4*)((const unsigned*)emb_bf + arow * 32 + h * 16 + quad * 4);
            uint4 ug = *pgr;
            uint4 ua = *par;
            aG[h] = *(const short8*)&ug;
            uint4 up;
            up.x = pack_bf2(bf_lo(ua.x) * bf_lo(ug.x), bf_hi(ua.x) * bf_hi(ug.x));
            up.y = pack_bf2(bf_lo(ua.y) * bf_lo(ug.y), bf_hi(ua.y) * bf_hi(ug.y));
            up.z = pack_bf2(bf_lo(ua.z) * bf_lo(ug.z), bf_hi(ua.z) * bf_hi(ug.z));
            up.w = pack_bf2(bf_lo(ua.w) * bf_lo(ug.w), bf_hi(ua.w) * bf_hi(ug.w));
            aAG[h] = *(const short8*)&up;
        }
        floatx4 accg[4], accb[4];
#pragma unroll
        for (int t = 0; t < 4; ++t) {
            accg[t] = (floatx4)(0.f);
            accb[t] = (floatx4)(0.f);
        }
#pragma unroll
        for (int t = 0; t < 4; ++t) {
#pragma unroll
            for (int h = 0; h < 2; ++h) {
                accg[t] = __builtin_amdgcn_mfma_f32_16x16x32_bf16(aG[h], bWg[t][h], accg[t], 0, 0, 0);
                accb[t] = __builtin_amdgcn_mfma_f32_16x16x32_bf16(aAG[h], bWb[t][h], accb[t], 0, 0, 0);
            }
        }
        float nv[4][4];
        float ss[4] = {0.f, 0.f, 0.f, 0.f};
#pragma unroll
        for (int i = 0; i < 4; ++i) {
            int r = rbase + quad * 4 + i;
#pragma unroll
            for (int t = 0; t < 4; ++t) {
                float a = embs[r * 64 + t * 16 + lanelo];
                float e1 = accg[t][i] + bgv[t] + a;
                e1 = e1 >= 0.f ? e1 : 0.2f * e1;
                float e2 = accb[t][i] + bbv[t];
                e2 = e2 >= 0.f ? e2 : 0.2f * e2;
                float v = e1 + e2;
                nv[i][t] = v;
                ss[i] += v * v;
            }
        }
#pragma unroll
        for (int m = 1; m < 16; m <<= 1) {
#pragma unroll
            for (int i = 0; i < 4; ++i) ss[i] += __shfl_xor(ss[i], m, 64);
        }
#pragma unroll
        for (int i = 0; i < 4; ++i) {
            int r = rbase + quad * 4 + i;
            float rn = 1.0f / fmaxf(sqrtf(ss[i]), 1e-12f);
#pragma unroll
            for (int t = 0; t < 4; ++t) {
                int idx = r * 64 + t * 16 + lanelo;
                float rr = nv[i][t] * rn;
                embs[idx] = rr;
                emb_bf[idx] = f2bf(rr);
                outacc[idx] = (outacc[idx] + rr) * finalScale;
            }
        }
    }
}

// ---------------- launch ----------------

extern "C" void kernel_launch(void* const* d_in, const int* in_sizes, int n_in,
                              void* d_out, int out_size, void* d_ws, size_t ws_size,
                              hipStream_t stream) {
    const float* u_emb = (const float*)d_in[0];
    const float* i_emb = (const float*)d_in[1];
    const float* Wgc = (const float*)d_in[2];
    const float* bgc = (const float*)d_in[3];
    const float* Wbi = (const float*)d_in[4];
    const float* bbi = (const float*)d_in[5];
    const int* edge_u = (const int*)d_in[6];
    const int* edge_i = (const int*)d_in[7];
    float* out = (float*)d_out;

    char* w = (char*)d_ws;
    auto alloc = [&](size_t bytes) {
        char* p = w;
        w += (bytes + 255) & ~(size_t)255;
        return p;
    };
    int* deg = (int*)alloc((size_t)NTOT * 4);
    int* start = (int*)alloc((size_t)NTOT * 4);
    int* cursor = (int*)alloc((size_t)NTOT * 4);
    int* partials = (int*)alloc(256 * 4);
    int* csr = (int*)alloc((size_t)2 * NE * 4);
    float* isq = (float*)alloc((size_t)NTOT * 4);
    float* inv = (float*)alloc((size_t)NTOT * 4);
    float* embs = (float*)alloc((size_t)NTOT * EDIM * 4);
    unsigned* emb_bf = (unsigned*)alloc((size_t)NTOT * EDIM * 2);
    unsigned* E_bf = (unsigned*)alloc((size_t)NTOT * EDIM * 2);
    unsigned* g_bf = (unsigned*)alloc((size_t)NTOT * EDIM * 2);
    // hist byte-planes (NSLICE * NWORDS * 4 = 19.2 MB) aliased onto embs
    // (38.4 MB): partial is dead before k_init writes embs.
    unsigned* hpartial = (unsigned*)embs;

    // graph prep: byte-packed LDS degree histogram (no global atomics)
    k_hist<<<NRANGE * NSLICE, 256, 0, stream>>>(edge_u, edge_i, hpartial);
    k_merge<<<(NWORDS + 255) / 256, 256, 0, stream>>>(hpartial, deg, isq, inv);
    k_blocksum<<<NBLK, 256, 0, stream>>>(deg, partials);
    k_scanpartials<<<1, 256, 0, stream>>>(partials, NBLK);
    k_scanfinal<<<NBLK, 256, 0, stream>>>(deg, partials, start, cursor);
    for (int p = 0; p < FILL_PASSES; ++p) {
        k_fill_pass<<<(NE + 255) / 256, 256, 0, stream>>>(
            edge_u, edge_i, cursor, csr, p * FILL_RANGE, (p + 1) * FILL_RANGE);
    }

    k_init<<<(NTOT * EDIM / 4 + 255) / 256, 256, 0, stream>>>(u_emb, i_emb, embs, out, emb_bf);

    const int gatherBlocks = (NTOT * 64 + 255) / 256;   // one wave per row
    for (int l = 0; l < NLAYERS; ++l) {
        // E[n] = inv[n] * sum isqrt[m]*embs[m]   (bf16 in, bf16 out)
        k_gather<true, true><<<gatherBlocks, 256, 0, stream>>>(
            emb_bf, E_bf, nullptr, csr, start, deg, inv, isq);
        // g[n] = isqrt[n] * sum E[m]             (bf16 in, bf16 out)
        k_gather<false, true><<<gatherBlocks, 256, 0, stream>>>(
            E_bf, g_bf, nullptr, csr, start, deg, isq, nullptr);
        float fs = (l == NLAYERS - 1) ? 0.25f : 1.0f;
        k_dense_mfma<<<1024, 256, 0, stream>>>(
            embs, g_bf, out, (unsigned short*)emb_bf,
            Wgc + (size_t)l * 4096, bgc + (size_t)l * 64,
            Wbi + (size_t)l * 4096, bbi + (size_t)l * 64, fs);
    }
}

// Round 6
// 707.255 us; speedup vs baseline: 1.7878x; 1.1438x over previous
//
#include <hip/hip_runtime.h>
#include <cstdint>
#include <cstddef>

#define NU 100000
#define NI 50000
#define NTOT 150000
#define EDIM 64
#define NE 1000000
#define NLAYERS 3
#define SCAN_CHUNK 1024
#define NBLK ((NTOT + SCAN_CHUNK - 1) / SCAN_CHUNK)   // 147
#define FILL_PASSES 8
#define FILL_RANGE (NTOT / FILL_PASSES)               // 18750
#define NTILES (NTOT / 16)                            // 9375

// byte-packed degree histogram: 4 nodes/word, 32768 nodes per 32KB block.
#define HB_BYTES 32768
#define HB_WORDS (HB_BYTES / 4)
#define NSLICE 128
#define ESLICE ((NE + NSLICE - 1) / NSLICE)           // 7813
#define NRANGE_U 4
#define NRANGE_I 2
#define NRANGE (NRANGE_U + NRANGE_I)
#define NWORDS (NTOT / 4)                             // 37500

typedef __attribute__((ext_vector_type(8))) short short8;   // 8 bf16 (4 VGPRs)
typedef __attribute__((ext_vector_type(4))) float floatx4;  // 4 fp32 acc

// ---------------- bf16 helpers (raw-bit, RNE) ----------------
__device__ inline unsigned short f2bf(float f) {
    unsigned u = __float_as_uint(f);
    u += 0x7fffu + ((u >> 16) & 1u);
    return (unsigned short)(u >> 16);
}
__device__ inline unsigned pack_bf2(float a, float b) {
    unsigned ua = __float_as_uint(a); ua += 0x7fffu + ((ua >> 16) & 1u);
    unsigned ub = __float_as_uint(b); ub += 0x7fffu + ((ub >> 16) & 1u);
    return (ua >> 16) | (ub & 0xffff0000u);
}
__device__ inline float bf_lo(unsigned u) { return __uint_as_float(u << 16); }
__device__ inline float bf_hi(unsigned u) { return __uint_as_float(u & 0xffff0000u); }

// ---------------- degree histogram, byte-packed LDS ----------------
__global__ __launch_bounds__(256) void k_hist(const int* __restrict__ eu,
                                              const int* __restrict__ ei,
                                              unsigned* __restrict__ partial) {
    __shared__ unsigned h[HB_WORDS];
    int r = blockIdx.x / NSLICE;
    int s = blockIdx.x % NSLICE;
    const int* arr;
    int base, gbyte, lim;
    if (r < NRANGE_U) {
        arr = eu; base = r * HB_BYTES; gbyte = base;
        lim = min(HB_BYTES, NU - base);
    } else {
        arr = ei; base = (r - NRANGE_U) * HB_BYTES; gbyte = NU + base;
        lim = min(HB_BYTES, NI - base);
    }
    for (int i = threadIdx.x; i < HB_WORDS; i += 256) h[i] = 0;
    __syncthreads();
    const int e0 = s * ESLICE, e1 = min(NE, e0 + ESLICE);
    for (int e = e0 + threadIdx.x; e < e1; e += 256) {
        unsigned local = (unsigned)(arr[e] - base);
        if (local < (unsigned)HB_BYTES)
            atomicAdd(&h[local >> 2], 1u << ((local & 3u) * 8u));
    }
    __syncthreads();
    unsigned* dst = partial + (size_t)s * NWORDS + (gbyte >> 2);
    int lw = lim >> 2;
    for (int i = threadIdx.x; i < lw; i += 256) dst[i] = h[i];
}

__global__ void k_merge(const unsigned* __restrict__ partial, int* __restrict__ deg,
                        float* __restrict__ isq, float* __restrict__ inv) {
    int n = blockIdx.x * blockDim.x + threadIdx.x;
    if (n >= NWORDS) return;
    unsigned se = 0, so = 0;
    for (int s = 0; s < NSLICE; ++s) {
        unsigned v = partial[(size_t)s * NWORDS + n];
        se += v & 0x00ff00ffu;
        so += (v >> 8) & 0x00ff00ffu;
    }
    int d[4];
    d[0] = se & 0xffff; d[1] = so & 0xffff;
    d[2] = se >> 16;    d[3] = so >> 16;
    ((int4*)deg)[n] = make_int4(d[0], d[1], d[2], d[3]);
    float4 q, iv;
    float* qp = &q.x; float* ip = &iv.x;
#pragma unroll
    for (int j = 0; j < 4; ++j) {
        float df = (float)d[j];
        qp[j] = d[j] > 0 ? 1.0f / sqrtf(df) : 0.f;
        ip[j] = d[j] > 0 ? 1.0f / df : 0.f;
    }
    ((float4*)isq)[n] = q;
    ((float4*)inv)[n] = iv;
}

// ---------------- scan kernels ----------------

__global__ void k_blocksum(const int* __restrict__ deg, int* __restrict__ partials) {
    __shared__ int sm[256];
    int b = blockIdx.x, t = threadIdx.x;
    int base = b * SCAN_CHUNK + t * 4;
    int s = 0;
#pragma unroll
    for (int j = 0; j < 4; ++j) {
        int idx = base + j;
        if (idx < NTOT) s += deg[idx];
    }
    sm[t] = s;
    __syncthreads();
    for (int off = 128; off > 0; off >>= 1) {
        if (t < off) sm[t] += sm[t + off];
        __syncthreads();
    }
    if (t == 0) partials[b] = sm[0];
}

__global__ void k_scanpartials(int* __restrict__ partials, int nblk) {
    __shared__ int sm[256];
    int t = threadIdx.x;
    int v = (t < nblk) ? partials[t] : 0;
    sm[t] = v;
    __syncthreads();
    for (int off = 1; off < 256; off <<= 1) {
        int tmp = (t >= off) ? sm[t - off] : 0;
        __syncthreads();
        sm[t] += tmp;
        __syncthreads();
    }
    if (t < nblk) partials[t] = sm[t] - v;   // exclusive
}

__global__ void k_scanfinal(const int* __restrict__ deg, const int* __restrict__ partials,
                            int* __restrict__ start, int* __restrict__ cursor) {
    __shared__ int sm[256];
    int b = blockIdx.x, t = threadIdx.x;
    int base = b * SCAN_CHUNK + t * 4;
    int v[4];
    int s = 0;
#pragma unroll
    for (int j = 0; j < 4; ++j) {
        int idx = base + j;
        v[j] = (idx < NTOT) ? deg[idx] : 0;
        s += v[j];
    }
    sm[t] = s;
    __syncthreads();
    for (int off = 1; off < 256; off <<= 1) {
        int tmp = (t >= off) ? sm[t - off] : 0;
        __syncthreads();
        sm[t] += tmp;
        __syncthreads();
    }
    int excl = partials[b] + sm[t] - s;
#pragma unroll
    for (int j = 0; j < 4; ++j) {
        int idx = base + j;
        if (idx < NTOT) {
            start[idx] = excl;
            cursor[idx] = excl;
            excl += v[j];
        }
    }
}

// range-filtered CSR fill
__global__ void k_fill_pass(const int* __restrict__ eu, const int* __restrict__ ei,
                            int* __restrict__ cursor, int* __restrict__ csr,
                            int lo, int hi) {
    int e = blockIdx.x * blockDim.x + threadIdx.x;
    if (e < NE) {
        int u = eu[e];
        int v = NU + ei[e];
        if (u >= lo && u < hi) {
            int p = atomicAdd(&cursor[u], 1);
            csr[p] = v;
        }
        if (v >= lo && v < hi) {
            int p = atomicAdd(&cursor[v], 1);
            csr[p] = u;
        }
    }
}

// W f32 -> bf16 pre-conversion (both matrices, all layers)
__global__ void k_prepw(const float* __restrict__ Wg, const float* __restrict__ Wb,
                        unsigned short* __restrict__ wgb, unsigned short* __restrict__ wbb) {
    int i = blockIdx.x * blockDim.x + threadIdx.x;   // per 4 elems
    const int n4 = NLAYERS * 4096 / 4;
    if (i < n4) {
        float4 g4 = ((const float4*)Wg)[i];
        float4 b4 = ((const float4*)Wb)[i];
        uint2 g, b;
        g.x = pack_bf2(g4.x, g4.y); g.y = pack_bf2(g4.z, g4.w);
        b.x = pack_bf2(b4.x, b4.y); b.y = pack_bf2(b4.z, b4.w);
        ((uint2*)wgb)[i] = g;
        ((uint2*)wbb)[i] = b;
    }
}

// init: snap0 = bf16(concat(u,i)); embS = bf16(isq*emb) into gbuf
__global__ void k_init(const float* __restrict__ ue, const float* __restrict__ ie,
                       const float* __restrict__ isq,
                       unsigned* __restrict__ snap0, unsigned* __restrict__ gbuf) {
    int i = blockIdx.x * blockDim.x + threadIdx.x;
    const int n4 = NTOT * EDIM / 4;
    if (i < n4) {
        const int nu4 = NU * EDIM / 4;
        float4 v = (i < nu4) ? ((const float4*)ue)[i] : ((const float4*)ie)[i - nu4];
        float s = isq[i >> 4];
        uint2 b, bs;
        b.x = pack_bf2(v.x, v.y);
        b.y = pack_bf2(v.z, v.w);
        bs.x = pack_bf2(v.x * s, v.y * s);
        bs.y = pack_bf2(v.z * s, v.w * s);
        ((uint2*)snap0)[i] = b;
        ((uint2*)gbuf)[i] = bs;
    }
}

// zero the sentinel row NTOT of the two gather-input buffers
__global__ void k_zerorow(unsigned* __restrict__ a, unsigned* __restrict__ b) {
    int t = threadIdx.x;
    if (t < 32) {
        a[NTOT * 32 + t] = 0;
        b[NTOT * 32 + t] = 0;
    }
}

// ---------------- sparse gather (pull), bf16 rows, unweighted ----------------
// out[n] = sA[n] * sum_{m in nbr(n)} in[m]. Out-of-range lanes read the zero
// sentinel row at index NTOT.
__global__ __launch_bounds__(256) void k_gather(
    const unsigned* __restrict__ in_bf, unsigned* __restrict__ out_bf,
    const int* __restrict__ csr, const int* __restrict__ start,
    const int* __restrict__ deg, const float* __restrict__ sA) {
    int gw = (blockIdx.x * 256 + threadIdx.x) >> 6;   // global wave = row
    int lane = threadIdx.x & 63;
    if (gw >= NTOT) return;
    int l2 = lane & 31;
    int h = lane >> 5;
    int s0 = start[gw];
    int dg = deg[gw];
    float acc0 = 0.f, acc1 = 0.f;
    for (int j0 = 0; j0 < dg; j0 += 64) {
        int lim = min(64, dg - j0);
        int nidx = NTOT;   // sentinel zero row
        if (lane < lim) nidx = csr[s0 + j0 + lane];
        for (int j = 0; j < lim; j += 8) {
            int m0 = __shfl(nidx, j + h);
            int m1 = __shfl(nidx, j + 2 + h);
            int m2 = __shfl(nidx, j + 4 + h);
            int m3 = __shfl(nidx, j + 6 + h);
            unsigned u0 = in_bf[m0 * 32 + l2];
            unsigned u1 = in_bf[m1 * 32 + l2];
            unsigned u2 = in_bf[m2 * 32 + l2];
            unsigned u3 = in_bf[m3 * 32 + l2];
            acc0 += bf_lo(u0);
            acc1 += bf_hi(u0);
            acc0 += bf_lo(u1);
            acc1 += bf_hi(u1);
            acc0 += bf_lo(u2);
            acc1 += bf_hi(u2);
            acc0 += bf_lo(u3);
            acc1 += bf_hi(u3);
        }
    }
    acc0 += __shfl_xor(acc0, 32);
    acc1 += __shfl_xor(acc1, 32);
    if (lane < 32) {
        float s = sA[gw];
        out_bf[gw * 32 + l2] = pack_bf2(s * acc0, s * acc1);
    }
}

// ---------------- dense per-row update via MFMA (all-bf16 state) ----------------
// One wave per 16-row tile. Reads g rows (from gbuf) + a rows (snap_prev),
// writes snap_l (bf16) and, if writeScaled, embS = isq*emb bf16 IN PLACE over
// gbuf (per-tile local: each wave's reads of its rows precede its writes;
// tiles are disjoint across waves). gbuf intentionally NOT __restrict__.
__global__ __launch_bounds__(256) void k_dense_mfma(
    const unsigned short* __restrict__ a_prev, unsigned* gbuf,
    unsigned short* __restrict__ snap_l, const float* __restrict__ isq,
    const unsigned short* __restrict__ wgb, const unsigned short* __restrict__ wbb,
    const float* __restrict__ bg, const float* __restrict__ bb, int writeScaled) {
    int lane = threadIdx.x & 63;
    int lanelo = lane & 15;
    int quad = lane >> 4;
    int wid = (blockIdx.x * blockDim.x + threadIdx.x) >> 6;
    if (wid >= NTILES) return;

    // B-fragments from pre-converted bf16 W (vector loads, no conversion)
    short8 bWg[4][2], bWb[4][2];
#pragma unroll
    for (int t = 0; t < 4; ++t) {
#pragma unroll
        for (int h = 0; h < 2; ++h) {
            int n = t * 16 + lanelo;
            int k0 = h * 32 + quad * 8;
            bWg[t][h] = *(const short8*)&wgb[n * 64 + k0];
            bWb[t][h] = *(const short8*)&wbb[n * 64 + k0];
        }
    }
    float bgv[4], bbv[4];
#pragma unroll
    for (int t = 0; t < 4; ++t) {
        bgv[t] = bg[t * 16 + lanelo];
        bbv[t] = bb[t * 16 + lanelo];
    }

    int rbase = wid * 16;
    int arow = rbase + lanelo;
    short8 aG[2], aAG[2];
#pragma unroll
    for (int h = 0; h < 2; ++h) {
        uint4 ug = *(const uint4*)(gbuf + arow * 32 + h * 16 + quad * 4);
        uint4 ua = *(const uint4*)((const unsigned*)a_prev + arow * 32 + h * 16 + quad * 4);
        aG[h] = *(const short8*)&ug;
        uint4 up;
        up.x = pack_bf2(bf_lo(ua.x) * bf_lo(ug.x), bf_hi(ua.x) * bf_hi(ug.x));
        up.y = pack_bf2(bf_lo(ua.y) * bf_lo(ug.y), bf_hi(ua.y) * bf_hi(ug.y));
        up.z = pack_bf2(bf_lo(ua.z) * bf_lo(ug.z), bf_hi(ua.z) * bf_hi(ug.z));
        up.w = pack_bf2(bf_lo(ua.w) * bf_lo(ug.w), bf_hi(ua.w) * bf_hi(ug.w));
        aAG[h] = *(const short8*)&up;
    }
    floatx4 accg[4], accb[4];
#pragma unroll
    for (int t = 0; t < 4; ++t) {
        accg[t] = (floatx4)(0.f);
        accb[t] = (floatx4)(0.f);
    }
#pragma unroll
    for (int t = 0; t < 4; ++t) {
#pragma unroll
        for (int h = 0; h < 2; ++h) {
            accg[t] = __builtin_amdgcn_mfma_f32_16x16x32_bf16(aG[h], bWg[t][h], accg[t], 0, 0, 0);
            accb[t] = __builtin_amdgcn_mfma_f32_16x16x32_bf16(aAG[h], bWb[t][h], accb[t], 0, 0, 0);
        }
    }
    // epilogue in C/D layout: row = rbase + quad*4 + i, col = t*16 + lanelo
    float nv[4][4];
    float ss[4] = {0.f, 0.f, 0.f, 0.f};
#pragma unroll
    for (int i = 0; i < 4; ++i) {
        int r = rbase + quad * 4 + i;
#pragma unroll
        for (int t = 0; t < 4; ++t) {
            float a = __uint_as_float((unsigned)a_prev[r * 64 + t * 16 + lanelo] << 16);
            float e1 = accg[t][i] + bgv[t] + a;
            e1 = e1 >= 0.f ? e1 : 0.2f * e1;
            float e2 = accb[t][i] + bbv[t];
            e2 = e2 >= 0.f ? e2 : 0.2f * e2;
            float v = e1 + e2;
            nv[i][t] = v;
            ss[i] += v * v;
        }
    }
#pragma unroll
    for (int m = 1; m < 16; m <<= 1) {
#pragma unroll
        for (int i = 0; i < 4; ++i) ss[i] += __shfl_xor(ss[i], m, 64);
    }
#pragma unroll
    for (int i = 0; i < 4; ++i) {
        int r = rbase + quad * 4 + i;
        float rn = 1.0f / fmaxf(sqrtf(ss[i]), 1e-12f);
        float sc = isq[r] * rn;
#pragma unroll
        for (int t = 0; t < 4; ++t) {
            int idx = r * 64 + t * 16 + lanelo;
            float rr = nv[i][t] * rn;
            snap_l[idx] = f2bf(rr);
            if (writeScaled)
                ((unsigned short*)gbuf)[idx] = f2bf(nv[i][t] * sc);
        }
    }
}

// final mean: out = 0.25*(init_f32 + snap1 + snap2 + snap3)
__global__ void k_out(const float* __restrict__ ue, const float* __restrict__ ie,
                      const unsigned* __restrict__ s1, const unsigned* __restrict__ s2,
                      const unsigned* __restrict__ s3, float* __restrict__ out) {
    int i = blockIdx.x * blockDim.x + threadIdx.x;   // per 4 elems
    const int n4 = NTOT * EDIM / 4;
    if (i >= n4) return;
    const int nu4 = NU * EDIM / 4;
    float4 v = (i < nu4) ? ((const float4*)ue)[i] : ((const float4*)ie)[i - nu4];
    uint2 a = ((const uint2*)s1)[i];
    uint2 b = ((const uint2*)s2)[i];
    uint2 c = ((const uint2*)s3)[i];
    float4 o;
    o.x = 0.25f * (v.x + bf_lo(a.x) + bf_lo(b.x) + bf_lo(c.x));
    o.y = 0.25f * (v.y + bf_hi(a.x) + bf_hi(b.x) + bf_hi(c.x));
    o.z = 0.25f * (v.z + bf_lo(a.y) + bf_lo(b.y) + bf_lo(c.y));
    o.w = 0.25f * (v.w + bf_hi(a.y) + bf_hi(b.y) + bf_hi(c.y));
    ((float4*)out)[i] = o;
}

// ---------------- launch ----------------

extern "C" void kernel_launch(void* const* d_in, const int* in_sizes, int n_in,
                              void* d_out, int out_size, void* d_ws, size_t ws_size,
                              hipStream_t stream) {
    const float* u_emb = (const float*)d_in[0];
    const float* i_emb = (const float*)d_in[1];
    const float* Wgc = (const float*)d_in[2];
    const float* bgc = (const float*)d_in[3];
    const float* Wbi = (const float*)d_in[4];
    const float* bbi = (const float*)d_in[5];
    const int* edge_u = (const int*)d_in[6];
    const int* edge_i = (const int*)d_in[7];
    float* out = (float*)d_out;

    char* w = (char*)d_ws;
    auto alloc = [&](size_t bytes) {
        char* p = w;
        w += (bytes + 255) & ~(size_t)255;
        return p;
    };
    const size_t ROWBYTES = (size_t)(NTOT + 1) * EDIM * 2;   // +1 sentinel row
    int* deg = (int*)alloc((size_t)NTOT * 4);
    int* start = (int*)alloc((size_t)NTOT * 4);
    int* cursor = (int*)alloc((size_t)NTOT * 4);
    int* partials = (int*)alloc(256 * 4);
    int* csr = (int*)alloc((size_t)2 * NE * 4);
    float* isq = (float*)alloc((size_t)NTOT * 4);
    float* inv = (float*)alloc((size_t)NTOT * 4);
    unsigned short* wgb = (unsigned short*)alloc((size_t)NLAYERS * 4096 * 2);
    unsigned short* wbb = (unsigned short*)alloc((size_t)NLAYERS * 4096 * 2);
    unsigned* snap0 = (unsigned*)alloc((size_t)NTOT * EDIM * 2);
    unsigned* snap1 = (unsigned*)alloc((size_t)NTOT * EDIM * 2);
    unsigned* snap2 = (unsigned*)alloc((size_t)NTOT * EDIM * 2);
    unsigned* Ebuf = (unsigned*)alloc(ROWBYTES);    // = hpartial = snap3
    unsigned* gbuf = (unsigned*)alloc(ROWBYTES);    // = embS (in-place)
    unsigned* hpartial = Ebuf;                      // 19.2 MB fits; dead pre-init
    unsigned* snap3 = Ebuf;                         // written by dense L3

    // graph prep
    k_hist<<<NRANGE * NSLICE, 256, 0, stream>>>(edge_u, edge_i, hpartial);
    k_merge<<<(NWORDS + 255) / 256, 256, 0, stream>>>(hpartial, deg, isq, inv);
    k_blocksum<<<NBLK, 256, 0, stream>>>(deg, partials);
    k_scanpartials<<<1, 256, 0, stream>>>(partials, NBLK);
    k_scanfinal<<<NBLK, 256, 0, stream>>>(deg, partials, start, cursor);
    for (int p = 0; p < FILL_PASSES; ++p) {
        k_fill_pass<<<(NE + 255) / 256, 256, 0, stream>>>(
            edge_u, edge_i, cursor, csr, p * FILL_RANGE, (p + 1) * FILL_RANGE);
    }
    k_prepw<<<(NLAYERS * 4096 / 4 + 255) / 256, 256, 0, stream>>>(Wgc, Wbi, wgb, wbb);
    k_init<<<(NTOT * EDIM / 4 + 255) / 256, 256, 0, stream>>>(u_emb, i_emb, isq, snap0, gbuf);
    k_zerorow<<<1, 64, 0, stream>>>(Ebuf, gbuf);

    const int gatherBlocks = (NTOT * 64 + 255) / 256;   // one wave per row
    const int denseBlocks = (NTILES * 64 + 255) / 256;  // one wave per 16-row tile
    const unsigned short* aprev[3] = {(unsigned short*)snap0, (unsigned short*)snap1,
                                      (unsigned short*)snap2};
    unsigned short* snaps[3] = {(unsigned short*)snap1, (unsigned short*)snap2,
                                (unsigned short*)snap3};
    for (int l = 0; l < NLAYERS; ++l) {
        // E[n] = inv[n] * sum embS[m]      (embS = isq*emb, pre-scaled)
        k_gather<<<gatherBlocks, 256, 0, stream>>>(gbuf, Ebuf, csr, start, deg, inv);
        // g[n] = isq[n] * sum E[m]
        k_gather<<<gatherBlocks, 256, 0, stream>>>(Ebuf, gbuf, csr, start, deg, isq);
        k_dense_mfma<<<denseBlocks, 256, 0, stream>>>(
            aprev[l], gbuf, snaps[l], isq, wgb + (size_t)l * 4096, wbb + (size_t)l * 4096,
            bgc + (size_t)l * 64, bbi + (size_t)l * 64, l < NLAYERS - 1 ? 1 : 0);
    }
    k_out<<<(NTOT * EDIM / 4 + 255) / 256, 256, 0, stream>>>(
        u_emb, i_emb, snap1, snap2, snap3, out);
}